// Round 6
// baseline (2212.843 us; speedup 1.0000x reference)
//
#include <hip/hip_runtime.h>
#include <hip/hip_bf16.h>

#define IN_CH 128
#define HID 32
#define OUT_CH 16
#define NPW 128          // nodes per bucket (col >> 7)
#define NPW_SHIFT 7
#define NB_MAX 1024
#define FB_GRID 256      // blocks in hist/fill (big chunks -> dense per-bucket runs)
#define EPT 4

typedef int vint4 __attribute__((ext_vector_type(4)));

// ---------------------------------------------------------------------------
// dtype sniffing: edge_index is int64 per the reference but may arrive int32.
// ---------------------------------------------------------------------------
__global__ void detect_dtype(const void* ei, long long ecount, int n, int* flag) {
    if (threadIdx.x == 0 && blockIdx.x == 0) {
        int is64 = 1;
        const long long* p = (const long long*)ei;
        long long st = ecount / 64; if (st < 1) st = 1;
        for (int j = 0; j < 64; ++j) {
            long long idx = (long long)j * st;
            if (idx >= ecount) break;
            long long v = p[idx];
            if (v < 0 || v >= n) { is64 = 0; break; }
        }
        *flag = is64;
    }
}

__device__ __forceinline__ int load_idx(const void* ei, long long i, int is64) {
    return is64 ? (int)((const long long*)ei)[i] : ((const int*)ei)[i];
}

__device__ __forceinline__ void load_idx4_nt(const void* ei, long long off, int is64,
                                             int* c) {
    if (is64) {
        const long long* p = (const long long*)ei + off;
        c[0] = (int)__builtin_nontemporal_load(p + 0);
        c[1] = (int)__builtin_nontemporal_load(p + 1);
        c[2] = (int)__builtin_nontemporal_load(p + 2);
        c[3] = (int)__builtin_nontemporal_load(p + 3);
    } else {
        vint4 v = __builtin_nontemporal_load((const vint4*)((const int*)ei + off));
        c[0] = v.x; c[1] = v.y; c[2] = v.z; c[3] = v.w;
    }
}

// ---------------------------------------------------------------------------
__global__ __launch_bounds__(256) void zero_int(int* p, int n) {
    int i = blockIdx.x * 256 + threadIdx.x;
    if (i < n) p[i] = 0;
}

__global__ __launch_bounds__(256) void zero_float(float* p, long long n) {
    long long i = (long long)blockIdx.x * 256 + threadIdx.x;
    if (i < n) p[i] = 0.f;
}

// ---------------------------------------------------------------------------
// bucket histogram: per-block LDS hist over its contiguous edge chunk, then
// one global atomicAdd per bucket. No scattered global atomics.
// ---------------------------------------------------------------------------
__global__ __launch_bounds__(256) void bucket_hist(const void* ei, long long E,
                                                   const int* flag, int* btot,
                                                   int nb, long long chunk) {
    __shared__ int hist[NB_MAX];
    for (int i = threadIdx.x; i < nb; i += 256) hist[i] = 0;
    __syncthreads();
    long long lo = (long long)blockIdx.x * chunk;
    long long hi = lo + chunk; if (hi > E) hi = E;
    int is64 = *flag;
    if ((E & 3) == 0) {
        for (long long e = lo + (long long)threadIdx.x * EPT; e + EPT <= hi;
             e += 256LL * EPT) {
            int c[4]; load_idx4_nt(ei, E + e, is64, c);
#pragma unroll
            for (int j = 0; j < 4; ++j) atomicAdd(&hist[c[j] >> NPW_SHIFT], 1);
        }
    } else {
        for (long long e = lo + threadIdx.x; e < hi; e += 256)
            atomicAdd(&hist[load_idx(ei, E + e, is64) >> NPW_SHIFT], 1);
    }
    __syncthreads();
    for (int b = threadIdx.x; b < nb; b += 256)
        if (hist[b]) atomicAdd(&btot[b], hist[b]);
}

// single-block exclusive scan over nb (<=1024) bucket totals
__global__ __launch_bounds__(1024) void scan_buckets(const int* btot, int* bstart,
                                                     int* bcursor, int nb) {
    __shared__ int sd[1024];
    int t = threadIdx.x;
    int v = (t < nb) ? btot[t] : 0;
    sd[t] = v; __syncthreads();
    for (int off = 1; off < 1024; off <<= 1) {
        int u = (t >= off) ? sd[t - off] : 0;
        __syncthreads(); sd[t] += u; __syncthreads();
    }
    if (t < nb) {
        int excl = sd[t] - v;
        bstart[t] = excl; bcursor[t] = excl;
        if (t == nb - 1) bstart[nb] = sd[t];
    }
}

// ---------------------------------------------------------------------------
// dense-write bucket fill: pass1 LDS hist of my chunk; grab contiguous range
// per bucket with ONE global atomic; pass2 re-read chunk (L2-hot) and write
// packed (row | lcol<<17) into my private contiguous runs. Write amp ~1.5x.
// ---------------------------------------------------------------------------
__global__ __launch_bounds__(256) void fill_bucket(const void* ei, long long E,
                                                   const int* flag, int* bcursor,
                                                   int* bucketed, int nb,
                                                   long long chunk) {
    __shared__ int hist[NB_MAX];
    __shared__ int base[NB_MAX];
    for (int i = threadIdx.x; i < nb; i += 256) hist[i] = 0;
    __syncthreads();
    long long lo = (long long)blockIdx.x * chunk;
    long long hi = lo + chunk; if (hi > E) hi = E;
    int is64 = *flag;
    bool vec = ((E & 3) == 0);
    if (vec) {
        for (long long e = lo + (long long)threadIdx.x * EPT; e + EPT <= hi;
             e += 256LL * EPT) {
            int c[4]; load_idx4_nt(ei, E + e, is64, c);
#pragma unroll
            for (int j = 0; j < 4; ++j) atomicAdd(&hist[c[j] >> NPW_SHIFT], 1);
        }
    } else {
        for (long long e = lo + threadIdx.x; e < hi; e += 256)
            atomicAdd(&hist[load_idx(ei, E + e, is64) >> NPW_SHIFT], 1);
    }
    __syncthreads();
    for (int b = threadIdx.x; b < nb; b += 256) {
        int hc = hist[b];
        if (hc) base[b] = atomicAdd(&bcursor[b], hc);
        hist[b] = 0;                      // becomes local cursor for pass 2
    }
    __syncthreads();
    if (vec) {
        for (long long e = lo + (long long)threadIdx.x * EPT; e + EPT <= hi;
             e += 256LL * EPT) {
            int c[4], r[4];
            load_idx4_nt(ei, E + e, is64, c);
            load_idx4_nt(ei, e, is64, r);
#pragma unroll
            for (int j = 0; j < 4; ++j) {
                int b = c[j] >> NPW_SHIFT;
                int pos = atomicAdd(&hist[b], 1);
                bucketed[base[b] + pos] = r[j] | ((c[j] & (NPW - 1)) << 17);
            }
        }
    } else {
        for (long long e = lo + threadIdx.x; e < hi; e += 256) {
            int col = load_idx(ei, E + e, is64);
            int row = load_idx(ei, e, is64);
            int b = col >> NPW_SHIFT;
            int pos = atomicAdd(&hist[b], 1);
            bucketed[base[b] + pos] = row | ((col & (NPW - 1)) << 17);
        }
    }
}

// per-bucket node degree from the bucketed list (dense reads, LDS hist)
__global__ __launch_bounds__(256) void node_cnt_dinv(const int* bucketed,
                                                     const int* bstart,
                                                     float* dinv, int n) {
    __shared__ int hc[NPW];
    int t = threadIdx.x;
    if (t < NPW) hc[t] = 0;
    __syncthreads();
    int b = blockIdx.x;
    for (int i = bstart[b] + t; i < bstart[b + 1]; i += 256)
        atomicAdd(&hc[bucketed[i] >> 17], 1);
    __syncthreads();
    if (t < NPW) {
        int node = b * NPW + t;
        if (node < n) dinv[node] = 1.0f / sqrtf((float)(hc[t] + 1));  // +1 self loop
    }
}

// ---------------------------------------------------------------------------
// GEMMs with dinv pre-multiplied into the output (kills per-edge dinv gather)
// ---------------------------------------------------------------------------
__global__ __launch_bounds__(256) void gemm1p(const float* __restrict__ x,
                                              const float* __restrict__ W1,
                                              const float* __restrict__ dinv,
                                              float* __restrict__ m1, int n) {
    __shared__ float sW[IN_CH * HID];
    __shared__ float sx[8][IN_CH];
    for (int i = threadIdx.x; i < IN_CH * HID; i += 256) sW[i] = W1[i];
    int g = threadIdx.x >> 5;
    int c = threadIdx.x & 31;
    long long node = (long long)blockIdx.x * 8 + g;
    bool active = node < n;
    if (active) {
        const float4* xr = (const float4*)(x + node * IN_CH);
        float4 v = xr[c];
        sx[g][c * 4 + 0] = v.x; sx[g][c * 4 + 1] = v.y;
        sx[g][c * 4 + 2] = v.z; sx[g][c * 4 + 3] = v.w;
    }
    __syncthreads();
    if (!active) return;
    float acc = 0.f;
#pragma unroll
    for (int k = 0; k < IN_CH; ++k)
        acc = fmaf(sx[g][k], sW[k * HID + c], acc);
    m1[node * HID + c] = acc * dinv[node];
}

__global__ __launch_bounds__(256) void gemm2p(const float* __restrict__ h,
                                              const float* __restrict__ W2,
                                              const float* __restrict__ dinv,
                                              float* __restrict__ m2, int n) {
    __shared__ float sW[HID * OUT_CH];
    for (int i = threadIdx.x; i < HID * OUT_CH; i += 256) sW[i] = W2[i];
    __syncthreads();
    long long t = (long long)blockIdx.x * 256 + threadIdx.x;
    long long node = t >> 4;
    int c = (int)(t & 15);
    if (node >= n) return;
    const float* hr = h + node * HID;
    float acc = 0.f;
#pragma unroll
    for (int k = 0; k < HID; ++k)
        acc = fmaf(hr[k], sW[k * OUT_CH + c], acc);
    m2[node * OUT_CH + c] = acc * dinv[node];
}

// ---------------------------------------------------------------------------
// bucket-wise aggregation: one block per bucket; LDS fp32 accumulator;
// dense edge reads; coalesced 128B m-row gathers; LDS float atomics
// (half-wave pairs hit banks 2-way = free).
// ---------------------------------------------------------------------------
__global__ __launch_bounds__(512) void agg1_bucket(const float* __restrict__ m1,
                                                   const int* __restrict__ bucketed,
                                                   const int* __restrict__ bstart,
                                                   const float* __restrict__ dinv,
                                                   const float* __restrict__ b1,
                                                   float* __restrict__ h, int n) {
    __shared__ float acc[NPW * HID];     // 16 KB
    int t = threadIdx.x;
    for (int i = t; i < NPW * HID; i += 512) acc[i] = 0.f;
    __syncthreads();
    int b = blockIdx.x;
    int s1 = bstart[b + 1];
    int p = t >> 5, c = t & 31;          // 16 edge slots x 32 channels
    int i = bstart[b] + p;
    for (; i + 48 < s1; i += 64) {
        int p0 = bucketed[i], p1 = bucketed[i + 16];
        int p2 = bucketed[i + 32], p3 = bucketed[i + 48];
        float v0 = m1[((long long)(p0 & 0x1FFFF) << 5) + c];
        float v1 = m1[((long long)(p1 & 0x1FFFF) << 5) + c];
        float v2 = m1[((long long)(p2 & 0x1FFFF) << 5) + c];
        float v3 = m1[((long long)(p3 & 0x1FFFF) << 5) + c];
        atomicAdd(&acc[((p0 >> 17) << 5) + c], v0);
        atomicAdd(&acc[((p1 >> 17) << 5) + c], v1);
        atomicAdd(&acc[((p2 >> 17) << 5) + c], v2);
        atomicAdd(&acc[((p3 >> 17) << 5) + c], v3);
    }
    for (; i < s1; i += 16) {
        int pk = bucketed[i];
        atomicAdd(&acc[((pk >> 17) << 5) + c],
                  m1[((long long)(pk & 0x1FFFF) << 5) + c]);
    }
    __syncthreads();
    for (int k = t; k < NPW * HID; k += 512) {
        int node = b * NPW + (k >> 5);
        if (node < n) {
            int cc = k & 31;
            float val = (acc[k] + m1[((long long)node << 5) + cc]) * dinv[node] + b1[cc];
            h[((long long)node << 5) + cc] = val > 0.f ? val : 0.f;
        }
    }
}

__global__ __launch_bounds__(512) void agg2_bucket(const float* __restrict__ m2,
                                                   const int* __restrict__ bucketed,
                                                   const int* __restrict__ bstart,
                                                   const float* __restrict__ dinv,
                                                   const float* __restrict__ b2,
                                                   float* __restrict__ out, int n) {
    __shared__ float acc[NPW * OUT_CH];  // 8 KB
    int t = threadIdx.x;
    for (int i = t; i < NPW * OUT_CH; i += 512) acc[i] = 0.f;
    __syncthreads();
    int b = blockIdx.x;
    int s1 = bstart[b + 1];
    int p = t >> 4, c = t & 15;          // 32 edge slots x 16 channels
    int i = bstart[b] + p;
    for (; i + 96 < s1; i += 128) {
        int p0 = bucketed[i], p1 = bucketed[i + 32];
        int p2 = bucketed[i + 64], p3 = bucketed[i + 96];
        float v0 = m2[((long long)(p0 & 0x1FFFF) << 4) + c];
        float v1 = m2[((long long)(p1 & 0x1FFFF) << 4) + c];
        float v2 = m2[((long long)(p2 & 0x1FFFF) << 4) + c];
        float v3 = m2[((long long)(p3 & 0x1FFFF) << 4) + c];
        atomicAdd(&acc[((p0 >> 17) << 4) + c], v0);
        atomicAdd(&acc[((p1 >> 17) << 4) + c], v1);
        atomicAdd(&acc[((p2 >> 17) << 4) + c], v2);
        atomicAdd(&acc[((p3 >> 17) << 4) + c], v3);
    }
    for (; i < s1; i += 32) {
        int pk = bucketed[i];
        atomicAdd(&acc[((pk >> 17) << 4) + c],
                  m2[((long long)(pk & 0x1FFFF) << 4) + c]);
    }
    __syncthreads();
    for (int k = t; k < NPW * OUT_CH; k += 512) {
        int node = b * NPW + (k >> 4);
        if (node < n) {
            int cc = k & 15;
            out[((long long)node << 4) + cc] =
                (acc[k] + m2[((long long)node << 4) + cc]) * dinv[node] + b2[cc];
        }
    }
}

// ---------------------------------------------------------------------------
// fallback path (small workspace / oversized n): scatter atomics
// ---------------------------------------------------------------------------
__global__ __launch_bounds__(256) void count_edges(const void* ei, int* cnt,
                                                   long long E, const int* flag) {
    long long e0 = ((long long)blockIdx.x * 256 + threadIdx.x) * EPT;
    if (e0 >= E) return;
    int is64 = *flag;
    if (e0 + EPT <= E && (E & 3) == 0) {
        int c[EPT];
        load_idx4_nt(ei, E + e0, is64, c);
#pragma unroll
        for (int j = 0; j < EPT; ++j) atomicAdd(&cnt[c[j]], 1);
    } else {
        for (long long e = e0; e < E && e < e0 + EPT; ++e)
            atomicAdd(&cnt[load_idx(ei, E + e, is64)], 1);
    }
}

__global__ __launch_bounds__(256) void compute_dinv(const int* cnt, float* dinv, int n) {
    int i = blockIdx.x * 256 + threadIdx.x;
    if (i < n) dinv[i] = 1.0f / sqrtf((float)(cnt[i] + 1));
}

__global__ __launch_bounds__(256) void gemm1f(const float* __restrict__ x,
                                              const float* __restrict__ W1,
                                              float* __restrict__ m1, int n) {
    __shared__ float sW[IN_CH * HID];
    __shared__ float sx[8][IN_CH];
    for (int i = threadIdx.x; i < IN_CH * HID; i += 256) sW[i] = W1[i];
    int g = threadIdx.x >> 5;
    int c = threadIdx.x & 31;
    long long node = (long long)blockIdx.x * 8 + g;
    bool active = node < n;
    if (active) {
        const float4* xr = (const float4*)(x + node * IN_CH);
        float4 v = xr[c];
        sx[g][c * 4 + 0] = v.x; sx[g][c * 4 + 1] = v.y;
        sx[g][c * 4 + 2] = v.z; sx[g][c * 4 + 3] = v.w;
    }
    __syncthreads();
    if (!active) return;
    float acc = 0.f;
#pragma unroll
    for (int k = 0; k < IN_CH; ++k)
        acc = fmaf(sx[g][k], sW[k * HID + c], acc);
    m1[node * HID + c] = acc;
}

__global__ __launch_bounds__(256) void gemm2f(const float* __restrict__ h,
                                              const float* __restrict__ W2,
                                              float* __restrict__ m2, int n) {
    __shared__ float sW[HID * OUT_CH];
    for (int i = threadIdx.x; i < HID * OUT_CH; i += 256) sW[i] = W2[i];
    __syncthreads();
    long long t = (long long)blockIdx.x * 256 + threadIdx.x;
    long long node = t >> 4;
    int c = (int)(t & 15);
    if (node >= n) return;
    const float* hr = h + node * HID;
    float acc = 0.f;
#pragma unroll
    for (int k = 0; k < HID; ++k)
        acc = fmaf(hr[k], sW[k * OUT_CH + c], acc);
    m2[node * OUT_CH + c] = acc;
}

__global__ __launch_bounds__(256) void scatter1(const float* __restrict__ m1,
                                                const void* ei, const float* __restrict__ dinv,
                                                float* __restrict__ h,
                                                long long E, const int* flag) {
    long long e = (long long)blockIdx.x * 8 + (threadIdx.x >> 5);
    int c = threadIdx.x & 31;
    if (e >= E) return;
    int is64 = *flag;
    int row = load_idx(ei, e, is64);
    int col = load_idx(ei, E + e, is64);
    float nrm = dinv[row] * dinv[col];
    atomicAdd(&h[(long long)col * HID + c], m1[(long long)row * HID + c] * nrm);
}

__global__ __launch_bounds__(256) void fixup1(const float* __restrict__ m1,
                                              const float* __restrict__ dinv,
                                              const float* __restrict__ b1,
                                              float* __restrict__ h, int n) {
    long long t = (long long)blockIdx.x * 256 + threadIdx.x;
    long long node = t >> 5; int c = (int)(t & 31);
    if (node >= n) return;
    float di = dinv[node];
    float v = h[node * HID + c] + m1[node * HID + c] * di * di + b1[c];
    h[node * HID + c] = v > 0.f ? v : 0.f;
}

__global__ __launch_bounds__(256) void scatter2(const float* __restrict__ m2, const void* ei,
                                                const float* __restrict__ dinv,
                                                float* __restrict__ out,
                                                long long E, const int* flag) {
    long long e = (long long)blockIdx.x * 16 + (threadIdx.x >> 4);
    int c = threadIdx.x & 15;
    if (e >= E) return;
    int is64 = *flag;
    int row = load_idx(ei, e, is64);
    int col = load_idx(ei, E + e, is64);
    float nrm = dinv[row] * dinv[col];
    atomicAdd(&out[(long long)col * OUT_CH + c], m2[(long long)row * OUT_CH + c] * nrm);
}

__global__ __launch_bounds__(256) void fixup2(const float* __restrict__ m2,
                                              const float* __restrict__ dinv,
                                              const float* __restrict__ b2,
                                              float* __restrict__ out, int n) {
    long long t = (long long)blockIdx.x * 256 + threadIdx.x;
    long long node = t >> 4; int c = (int)(t & 15);
    if (node >= n) return;
    float di = dinv[node];
    out[node * OUT_CH + c] += m2[node * OUT_CH + c] * di * di + b2[c];
}

// ---------------------------------------------------------------------------
extern "C" void kernel_launch(void* const* d_in, const int* in_sizes, int n_in,
                              void* d_out, int out_size, void* d_ws, size_t ws_size,
                              hipStream_t stream) {
    const float* x  = (const float*)d_in[0];
    const void*  ei = d_in[1];
    const float* W1 = (const float*)d_in[2];
    const float* b1 = (const float*)d_in[3];
    const float* W2 = (const float*)d_in[4];
    const float* b2 = (const float*)d_in[5];
    float* out = (float*)d_out;

    const int n = in_sizes[0] / IN_CH;           // 100000
    const long long E = in_sizes[1] / 2;         // 6400000
    const int nb = (n + NPW - 1) / NPW;          // 782

    char* w = (char*)d_ws;
    size_t used = 0;
    auto carve = [&](size_t bytes) -> void* {
        void* p = (void*)(w + used);
        used += (bytes + 255) & ~(size_t)255;
        return p;
    };
    auto A = [](size_t b) -> size_t { return (b + 255) & ~(size_t)255; };

    int*   bstart  = (int*)carve((size_t)(NB_MAX + 1) * 4);
    int*   bcursor = (int*)carve((size_t)NB_MAX * 4);
    int*   btot    = (int*)carve((size_t)NB_MAX * 4);
    float* dinv    = (float*)carve((size_t)n * 4);
    int*   flag    = (int*)carve(256);
    int*   cnt     = (int*)carve((size_t)n * 4);   // fallback only
    const size_t base = used;

    const size_t needT1 = base + A((size_t)E * 4) + 2 * A((size_t)n * HID * 4);
    const size_t needT2 = base + 2 * A((size_t)n * HID * 4);
    const bool tier1 = (ws_size >= needT1) && (n <= 131071) && (nb <= NB_MAX);

    const int nblkN = (n + 255) / 256;
    const int nblkO = (int)(((long long)n * OUT_CH + 255) / 256);
    const int nblkH = (int)(((long long)n * HID + 255) / 256);

    detect_dtype<<<1, 64, 0, stream>>>(ei, E, n, flag);

    if (tier1) {
        int*   bucketed = (int*)carve((size_t)E * 4);
        float* m1 = (float*)carve((size_t)n * HID * 4);
        float* h  = (float*)carve((size_t)n * HID * 4);
        float* m2 = m1;                            // m1 dead after agg1

        const long long chunk = (((E + FB_GRID - 1) / FB_GRID) + 3) & ~3LL;

        zero_int<<<(nb + 255) / 256, 256, 0, stream>>>(btot, nb);
        bucket_hist<<<FB_GRID, 256, 0, stream>>>(ei, E, flag, btot, nb, chunk);
        scan_buckets<<<1, 1024, 0, stream>>>(btot, bstart, bcursor, nb);
        fill_bucket<<<FB_GRID, 256, 0, stream>>>(ei, E, flag, bcursor, bucketed, nb, chunk);
        node_cnt_dinv<<<nb, 256, 0, stream>>>(bucketed, bstart, dinv, n);

        gemm1p<<<(n + 7) / 8, 256, 0, stream>>>(x, W1, dinv, m1, n);
        agg1_bucket<<<nb, 512, 0, stream>>>(m1, bucketed, bstart, dinv, b1, h, n);
        gemm2p<<<nblkO, 256, 0, stream>>>(h, W2, dinv, m2, n);
        agg2_bucket<<<nb, 512, 0, stream>>>(m2, bucketed, bstart, dinv, b2, out, n);
    } else if (ws_size >= needT2) {
        float* m1 = (float*)carve((size_t)n * HID * 4);
        float* h  = (float*)carve((size_t)n * HID * 4);
        float* m2 = m1;

        zero_int<<<nblkN, 256, 0, stream>>>(cnt, n);
        count_edges<<<(int)((E + 256LL * EPT - 1) / (256LL * EPT)), 256, 0, stream>>>(ei, cnt, E, flag);
        compute_dinv<<<nblkN, 256, 0, stream>>>(cnt, dinv, n);

        gemm1f<<<(n + 7) / 8, 256, 0, stream>>>(x, W1, m1, n);
        zero_float<<<nblkH, 256, 0, stream>>>(h, (long long)n * HID);
        scatter1<<<(int)((E + 7) / 8), 256, 0, stream>>>(m1, ei, dinv, h, E, flag);
        fixup1<<<nblkH, 256, 0, stream>>>(m1, dinv, b1, h, n);
        gemm2f<<<nblkO, 256, 0, stream>>>(h, W2, m2, n);
        zero_float<<<nblkO, 256, 0, stream>>>(out, (long long)n * OUT_CH);
        scatter2<<<(int)((E + 15) / 16), 256, 0, stream>>>(m2, ei, dinv, out, E, flag);
        fixup2<<<nblkO, 256, 0, stream>>>(m2, dinv, b2, out, n);
    }
    // (no tier for pathologically tiny ws; harness provides adequate ws)
}

// Round 7
// 438.911 us; speedup vs baseline: 5.0417x; 5.0417x over previous
//
#include <hip/hip_runtime.h>
#include <hip/hip_bf16.h>

#define IN_CH 128
#define HID 32
#define OUT_CH 16
#define NPW 64            // nodes per bucket (col >> 6)
#define NPW_SHIFT 6
#define NB_MAX 2048
#define FB_GRID 256       // blocks in hist/fill
#define CAP 12288         // LDS edge capacity in csr_sort (48 KB)
#define SCAN_CHUNK 1024
#define NXCD 8
#define EPT 4

typedef int vint4 __attribute__((ext_vector_type(4)));

// ---------------------------------------------------------------------------
__global__ void detect_dtype(const void* ei, long long ecount, int n, int* flag) {
    if (threadIdx.x == 0 && blockIdx.x == 0) {
        int is64 = 1;
        const long long* p = (const long long*)ei;
        long long st = ecount / 64; if (st < 1) st = 1;
        for (int j = 0; j < 64; ++j) {
            long long idx = (long long)j * st;
            if (idx >= ecount) break;
            long long v = p[idx];
            if (v < 0 || v >= n) { is64 = 0; break; }
        }
        *flag = is64;
    }
}

__device__ __forceinline__ int load_idx(const void* ei, long long i, int is64) {
    return is64 ? (int)((const long long*)ei)[i] : ((const int*)ei)[i];
}

__device__ __forceinline__ void load_idx4_nt(const void* ei, long long off, int is64,
                                             int* c) {
    if (is64) {
        const long long* p = (const long long*)ei + off;
        c[0] = (int)__builtin_nontemporal_load(p + 0);
        c[1] = (int)__builtin_nontemporal_load(p + 1);
        c[2] = (int)__builtin_nontemporal_load(p + 2);
        c[3] = (int)__builtin_nontemporal_load(p + 3);
    } else {
        vint4 v = __builtin_nontemporal_load((const vint4*)((const int*)ei + off));
        c[0] = v.x; c[1] = v.y; c[2] = v.z; c[3] = v.w;
    }
}

// ---------------------------------------------------------------------------
__global__ __launch_bounds__(256) void zero_int(int* p, int n) {
    int i = blockIdx.x * 256 + threadIdx.x;
    if (i < n) p[i] = 0;
}

__global__ __launch_bounds__(256) void zero_float(float* p, long long n) {
    long long i = (long long)blockIdx.x * 256 + threadIdx.x;
    if (i < n) p[i] = 0.f;
}

// ---------------------------------------------------------------------------
// bucket histogram: per-block LDS hist of its contiguous chunk -> one global
// atomicAdd per touched bucket.
// ---------------------------------------------------------------------------
__global__ __launch_bounds__(256) void bucket_hist(const void* ei, long long E,
                                                   const int* flag, int* btot,
                                                   int nb, long long chunk) {
    __shared__ int hist[NB_MAX];
    for (int i = threadIdx.x; i < nb; i += 256) hist[i] = 0;
    __syncthreads();
    long long lo = (long long)blockIdx.x * chunk;
    long long hi = lo + chunk; if (hi > E) hi = E;
    int is64 = *flag;
    if ((E & 3) == 0) {
        for (long long e = lo + (long long)threadIdx.x * EPT; e + EPT <= hi;
             e += 256LL * EPT) {
            int c[4]; load_idx4_nt(ei, E + e, is64, c);
#pragma unroll
            for (int j = 0; j < 4; ++j) atomicAdd(&hist[c[j] >> NPW_SHIFT], 1);
        }
    } else {
        for (long long e = lo + threadIdx.x; e < hi; e += 256)
            atomicAdd(&hist[load_idx(ei, E + e, is64) >> NPW_SHIFT], 1);
    }
    __syncthreads();
    for (int b = threadIdx.x; b < nb; b += 256)
        if (hist[b]) atomicAdd(&btot[b], hist[b]);
}

// pair-based exclusive scan over nb (<= 2048) bucket totals, one block
__global__ __launch_bounds__(1024) void scan_buckets(const int* btot, int* bstart,
                                                     int* bcursor, int nb) {
    __shared__ int sd[1024];
    int t = threadIdx.x;
    int a0 = (2 * t < nb) ? btot[2 * t] : 0;
    int a1 = (2 * t + 1 < nb) ? btot[2 * t + 1] : 0;
    sd[t] = a0 + a1; __syncthreads();
    for (int off = 1; off < 1024; off <<= 1) {
        int v = (t >= off) ? sd[t - off] : 0;
        __syncthreads(); sd[t] += v; __syncthreads();
    }
    int excl = sd[t] - (a0 + a1);
    if (2 * t < nb)     { bstart[2 * t] = excl;      bcursor[2 * t] = excl; }
    if (2 * t + 1 < nb) { bstart[2 * t + 1] = excl + a0; bcursor[2 * t + 1] = excl + a0; }
    if (t == 1023) bstart[nb] = sd[t];
}

// ---------------------------------------------------------------------------
// dense-write bucket fill: LDS hist -> one global atomic per bucket reserves a
// contiguous run -> packed (row | lcol<<17) written densely.
// ---------------------------------------------------------------------------
__global__ __launch_bounds__(256) void fill_bucket(const void* ei, long long E,
                                                   const int* flag, int* bcursor,
                                                   int* bucketed, int nb,
                                                   long long chunk) {
    __shared__ int hist[NB_MAX];
    __shared__ int base[NB_MAX];
    for (int i = threadIdx.x; i < nb; i += 256) hist[i] = 0;
    __syncthreads();
    long long lo = (long long)blockIdx.x * chunk;
    long long hi = lo + chunk; if (hi > E) hi = E;
    int is64 = *flag;
    bool vec = ((E & 3) == 0);
    if (vec) {
        for (long long e = lo + (long long)threadIdx.x * EPT; e + EPT <= hi;
             e += 256LL * EPT) {
            int c[4]; load_idx4_nt(ei, E + e, is64, c);
#pragma unroll
            for (int j = 0; j < 4; ++j) atomicAdd(&hist[c[j] >> NPW_SHIFT], 1);
        }
    } else {
        for (long long e = lo + threadIdx.x; e < hi; e += 256)
            atomicAdd(&hist[load_idx(ei, E + e, is64) >> NPW_SHIFT], 1);
    }
    __syncthreads();
    for (int b = threadIdx.x; b < nb; b += 256) {
        int hc = hist[b];
        if (hc) base[b] = atomicAdd(&bcursor[b], hc);
        hist[b] = 0;                      // local cursor for pass 2
    }
    __syncthreads();
    if (vec) {
        for (long long e = lo + (long long)threadIdx.x * EPT; e + EPT <= hi;
             e += 256LL * EPT) {
            int c[4], r[4];
            load_idx4_nt(ei, E + e, is64, c);
            load_idx4_nt(ei, e, is64, r);
#pragma unroll
            for (int j = 0; j < 4; ++j) {
                int b = c[j] >> NPW_SHIFT;
                int pos = atomicAdd(&hist[b], 1);
                bucketed[base[b] + pos] = r[j] | ((c[j] & (NPW - 1)) << 17);
            }
        }
    } else {
        for (long long e = lo + threadIdx.x; e < hi; e += 256) {
            int col = load_idx(ei, E + e, is64);
            int row = load_idx(ei, e, is64);
            int b = col >> NPW_SHIFT;
            int pos = atomicAdd(&hist[b], 1);
            bucketed[base[b] + pos] = row | ((col & (NPW - 1)) << 17);
        }
    }
}

// ---------------------------------------------------------------------------
// per-bucket node sort: LDS-stage bucket edges, 64-node hist, serial scan,
// emit offs/dinv + node-sorted csr (rows only). All dense global IO.
// ---------------------------------------------------------------------------
__global__ __launch_bounds__(512) void csr_sort(const int* __restrict__ bucketed,
                                                const int* __restrict__ bstart,
                                                int* __restrict__ csr,
                                                int* __restrict__ offs,
                                                float* __restrict__ dinv,
                                                int nb, int n) {
    __shared__ int lds_e[CAP];
    __shared__ int hist[NPW];
    __shared__ int cur[NPW];
    int b = blockIdx.x, t = threadIdx.x;
    int s0 = bstart[b], s1 = bstart[b + 1];
    int cnt = s1 - s0;
    if (t < NPW) hist[t] = 0;
    __syncthreads();
    bool fit = (cnt <= CAP);
    if (fit) {
        for (int i = t; i < cnt; i += 512) {
            int e = bucketed[s0 + i];
            lds_e[i] = e;
            atomicAdd(&hist[e >> 17], 1);
        }
    } else {
        for (int i = t; i < cnt; i += 512)
            atomicAdd(&hist[bucketed[s0 + i] >> 17], 1);
    }
    __syncthreads();
    if (t == 0) {
        int run = 0;
        for (int k = 0; k < NPW; ++k) { cur[k] = run; run += hist[k]; }
    }
    __syncthreads();
    if (t < NPW) {
        int node = b * NPW + t;
        if (node < n) {
            offs[node] = s0 + cur[t];
            dinv[node] = 1.0f / sqrtf((float)(hist[t] + 1));  // +1 self loop
        }
    }
    if (b == nb - 1 && t == 0) offs[n] = s1;
    __syncthreads();
    if (fit) {
        for (int i = t; i < cnt; i += 512) {
            int e = lds_e[i];
            int pos = atomicAdd(&cur[e >> 17], 1);
            csr[s0 + pos] = e & 0x1FFFF;
        }
    } else {
        for (int i = t; i < cnt; i += 512) {
            int e = bucketed[s0 + i];
            int pos = atomicAdd(&cur[e >> 17], 1);
            csr[s0 + pos] = e & 0x1FFFF;
        }
    }
}

// ---------------------------------------------------------------------------
// GEMMs with dinv pre-multiplied (kills per-edge dinv gather in agg)
// ---------------------------------------------------------------------------
__global__ __launch_bounds__(256) void gemm1p(const float* __restrict__ x,
                                              const float* __restrict__ W1,
                                              const float* __restrict__ dinv,
                                              float* __restrict__ m1, int n) {
    __shared__ float sW[IN_CH * HID];
    __shared__ float sx[8][IN_CH];
    for (int i = threadIdx.x; i < IN_CH * HID; i += 256) sW[i] = W1[i];
    int g = threadIdx.x >> 5;
    int c = threadIdx.x & 31;
    long long node = (long long)blockIdx.x * 8 + g;
    bool active = node < n;
    if (active) {
        const float4* xr = (const float4*)(x + node * IN_CH);
        float4 v = xr[c];
        sx[g][c * 4 + 0] = v.x; sx[g][c * 4 + 1] = v.y;
        sx[g][c * 4 + 2] = v.z; sx[g][c * 4 + 3] = v.w;
    }
    __syncthreads();
    if (!active) return;
    float acc = 0.f;
#pragma unroll
    for (int k = 0; k < IN_CH; ++k)
        acc = fmaf(sx[g][k], sW[k * HID + c], acc);
    m1[node * HID + c] = acc * dinv[node];
}

__global__ __launch_bounds__(256) void gemm2p(const float* __restrict__ h,
                                              const float* __restrict__ W2,
                                              const float* __restrict__ dinv,
                                              float* __restrict__ m2, int n) {
    __shared__ float sW[HID * OUT_CH];
    for (int i = threadIdx.x; i < HID * OUT_CH; i += 256) sW[i] = W2[i];
    __syncthreads();
    long long t = (long long)blockIdx.x * 256 + threadIdx.x;
    long long node = t >> 4;
    int c = (int)(t & 15);
    if (node >= n) return;
    const float* hr = h + node * HID;
    float acc = 0.f;
#pragma unroll
    for (int k = 0; k < HID; ++k)
        acc = fmaf(hr[k], sW[k * OUT_CH + c], acc);
    m2[node * OUT_CH + c] = acc * dinv[node];
}

// ---------------------------------------------------------------------------
// CSR gather aggregation (high parallelism; m pre-scaled -> no dinv gather)
// ---------------------------------------------------------------------------
__global__ __launch_bounds__(256) void agg1(const float* __restrict__ m1s,
                                            const int* __restrict__ csr,
                                            const int* __restrict__ offs,
                                            const float* __restrict__ dinv,
                                            const float* __restrict__ b1,
                                            float* __restrict__ h, int n) {
    int g = threadIdx.x >> 5;
    int c = threadIdx.x & 31;
    long long node = (long long)blockIdx.x * 8 + g;
    if (node >= n) return;
    float acc = m1s[(node << 5) + c];      // self loop
    int s = offs[node], e1 = offs[node + 1];
    for (; s + 3 < e1; s += 4) {
        int s0 = csr[s], s1 = csr[s + 1], s2 = csr[s + 2], s3 = csr[s + 3];
        float v0 = m1s[((long long)s0 << 5) + c];
        float v1 = m1s[((long long)s1 << 5) + c];
        float v2 = m1s[((long long)s2 << 5) + c];
        float v3 = m1s[((long long)s3 << 5) + c];
        acc += v0; acc += v1; acc += v2; acc += v3;
    }
    for (; s < e1; ++s) acc += m1s[((long long)csr[s] << 5) + c];
    float val = acc * dinv[node] + b1[c];
    h[(node << 5) + c] = val > 0.f ? val : 0.f;
}

__global__ __launch_bounds__(256) void agg2(const float* __restrict__ m2s,
                                            const int* __restrict__ csr,
                                            const int* __restrict__ offs,
                                            const float* __restrict__ dinv,
                                            const float* __restrict__ b2,
                                            float* __restrict__ out, int n) {
    int g = threadIdx.x >> 4;
    int c = threadIdx.x & 15;
    long long node = (long long)blockIdx.x * 16 + g;
    if (node >= n) return;
    float acc = m2s[(node << 4) + c];
    int s = offs[node], e1 = offs[node + 1];
    for (; s + 3 < e1; s += 4) {
        int s0 = csr[s], s1 = csr[s + 1], s2 = csr[s + 2], s3 = csr[s + 3];
        float v0 = m2s[((long long)s0 << 4) + c];
        float v1 = m2s[((long long)s1 << 4) + c];
        float v2 = m2s[((long long)s2 << 4) + c];
        float v3 = m2s[((long long)s3 << 4) + c];
        acc += v0; acc += v1; acc += v2; acc += v3;
    }
    for (; s < e1; ++s) acc += m2s[((long long)csr[s] << 4) + c];
    out[(node << 4) + c] = acc * dinv[node] + b2[c];
}

// ---------------------------------------------------------------------------
// tier 2: round-5 windowed CSR fill (+ node-count path)
// ---------------------------------------------------------------------------
__global__ __launch_bounds__(256) void count_edges(const void* ei, int* cnt,
                                                   long long E, const int* flag) {
    long long e0 = ((long long)blockIdx.x * 256 + threadIdx.x) * EPT;
    if (e0 >= E) return;
    int is64 = *flag;
    if (e0 + EPT <= E && (E & 3) == 0) {
        int c[EPT];
        load_idx4_nt(ei, E + e0, is64, c);
#pragma unroll
        for (int j = 0; j < EPT; ++j) atomicAdd(&cnt[c[j]], 1);
    } else {
        for (long long e = e0; e < E && e < e0 + EPT; ++e)
            atomicAdd(&cnt[load_idx(ei, E + e, is64)], 1);
    }
}

__global__ __launch_bounds__(256) void compute_dinv(const int* cnt, float* dinv, int n) {
    int i = blockIdx.x * 256 + threadIdx.x;
    if (i < n) dinv[i] = 1.0f / sqrtf((float)(cnt[i] + 1));
}

__global__ __launch_bounds__(256) void scan_partial(const int* cnt, int* partial, int n) {
    __shared__ int sd[256];
    int base = blockIdx.x * SCAN_CHUNK;
    int s = 0;
    for (int j = threadIdx.x; j < SCAN_CHUNK; j += 256) {
        int i = base + j;
        if (i < n) s += cnt[i];
    }
    sd[threadIdx.x] = s;
    __syncthreads();
    for (int off = 128; off > 0; off >>= 1) {
        if (threadIdx.x < off) sd[threadIdx.x] += sd[threadIdx.x + off];
        __syncthreads();
    }
    if (threadIdx.x == 0) partial[blockIdx.x] = sd[0];
}

__global__ void scan_serial(int* partial, int* offs, int nblk, int n) {
    if (threadIdx.x == 0 && blockIdx.x == 0) {
        int run = 0;
        for (int b = 0; b < nblk; ++b) { int t = partial[b]; partial[b] = run; run += t; }
        offs[n] = run;
    }
}

__global__ __launch_bounds__(256) void scan_final(const int* cnt, const int* partial,
                                                  int* offs, int n) {
    __shared__ int sd[256];
    int base = blockIdx.x * SCAN_CHUNK;
    int t = threadIdx.x;
    int loc[4]; int ts = 0;
#pragma unroll
    for (int j = 0; j < 4; ++j) {
        int i = base + t * 4 + j;
        loc[j] = (i < n) ? cnt[i] : 0;
        ts += loc[j];
    }
    sd[t] = ts;
    __syncthreads();
    for (int off = 1; off < 256; off <<= 1) {
        int v = (t >= off) ? sd[t - off] : 0;
        __syncthreads();
        sd[t] += v;
        __syncthreads();
    }
    int excl = sd[t] - ts + partial[blockIdx.x];
#pragma unroll
    for (int j = 0; j < 4; ++j) {
        int i = base + t * 4 + j;
        if (i < n) offs[i] = excl;
        excl += loc[j];
    }
}

__global__ __launch_bounds__(256) void copy_int(const int* src, int* dst, int n) {
    int i = blockIdx.x * 256 + threadIdx.x;
    if (i < n) dst[i] = src[i];
}

__global__ __launch_bounds__(256) void fill_csr_win(const void* ei, int* cursor, int* csr,
                                                    long long E, const int* flag,
                                                    int npw, int n) {
    int w = blockIdx.x & (NXCD - 1);
    int b = blockIdx.x >> 3;
    int lo = w * npw;
    int hi = lo + npw; if (hi > n) hi = n;
    long long e0 = ((long long)b * 256 + threadIdx.x) * EPT;
    if (e0 >= E) return;
    int is64 = *flag;
    if (e0 + EPT <= E && (E & 3) == 0) {
        int c[EPT];
        load_idx4_nt(ei, E + e0, is64, c);
#pragma unroll
        for (int j = 0; j < EPT; ++j) {
            if (c[j] >= lo && c[j] < hi) {
                int row = load_idx(ei, e0 + j, is64);
                int pos = atomicAdd(&cursor[c[j]], 1);
                csr[pos] = row;
            }
        }
    } else {
        for (long long e = e0; e < E && e < e0 + EPT; ++e) {
            int col = load_idx(ei, E + e, is64);
            if (col >= lo && col < hi) {
                int row = load_idx(ei, e, is64);
                int pos = atomicAdd(&cursor[col], 1);
                csr[pos] = row;
            }
        }
    }
}

// ---------------------------------------------------------------------------
// tier 3: scatter fallback (m pre-scaled -> scatter adds raw rows)
// ---------------------------------------------------------------------------
__global__ __launch_bounds__(256) void scatter1(const float* __restrict__ m1s,
                                                const void* ei,
                                                float* __restrict__ h,
                                                long long E, const int* flag) {
    long long e = (long long)blockIdx.x * 8 + (threadIdx.x >> 5);
    int c = threadIdx.x & 31;
    if (e >= E) return;
    int is64 = *flag;
    int row = load_idx(ei, e, is64);
    int col = load_idx(ei, E + e, is64);
    atomicAdd(&h[(long long)col * HID + c], m1s[(long long)row * HID + c]);
}

__global__ __launch_bounds__(256) void fixup1(const float* __restrict__ m1s,
                                              const float* __restrict__ dinv,
                                              const float* __restrict__ b1,
                                              float* __restrict__ h, int n) {
    long long t = (long long)blockIdx.x * 256 + threadIdx.x;
    long long node = t >> 5; int c = (int)(t & 31);
    if (node >= n) return;
    float v = (h[node * HID + c] + m1s[node * HID + c]) * dinv[node] + b1[c];
    h[node * HID + c] = v > 0.f ? v : 0.f;
}

__global__ __launch_bounds__(256) void scatter2(const float* __restrict__ m2s,
                                                const void* ei,
                                                float* __restrict__ out,
                                                long long E, const int* flag) {
    long long e = (long long)blockIdx.x * 16 + (threadIdx.x >> 4);
    int c = threadIdx.x & 15;
    if (e >= E) return;
    int is64 = *flag;
    int row = load_idx(ei, e, is64);
    int col = load_idx(ei, E + e, is64);
    atomicAdd(&out[(long long)col * OUT_CH + c], m2s[(long long)row * OUT_CH + c]);
}

__global__ __launch_bounds__(256) void fixup2(const float* __restrict__ m2s,
                                              const float* __restrict__ dinv,
                                              const float* __restrict__ b2,
                                              float* __restrict__ out, int n) {
    long long t = (long long)blockIdx.x * 256 + threadIdx.x;
    long long node = t >> 4; int c = (int)(t & 15);
    if (node >= n) return;
    out[node * OUT_CH + c] = (out[node * OUT_CH + c] + m2s[node * OUT_CH + c]) * dinv[node] + b2[c];
}

// ---------------------------------------------------------------------------
extern "C" void kernel_launch(void* const* d_in, const int* in_sizes, int n_in,
                              void* d_out, int out_size, void* d_ws, size_t ws_size,
                              hipStream_t stream) {
    const float* x  = (const float*)d_in[0];
    const void*  ei = d_in[1];
    const float* W1 = (const float*)d_in[2];
    const float* b1 = (const float*)d_in[3];
    const float* W2 = (const float*)d_in[4];
    const float* b2 = (const float*)d_in[5];
    float* out = (float*)d_out;

    const int n = in_sizes[0] / IN_CH;           // 100000
    const long long E = in_sizes[1] / 2;         // 6400000
    const int nb = (n + NPW - 1) / NPW;          // 1563

    char* w = (char*)d_ws;
    size_t used = 0;
    auto carve = [&](size_t bytes) -> void* {
        void* p = (void*)(w + used);
        used += (bytes + 255) & ~(size_t)255;
        return p;
    };
    auto A = [](size_t b) -> size_t { return (b + 255) & ~(size_t)255; };

    int*   bstart  = (int*)carve((size_t)(NB_MAX + 1) * 4);
    int*   bcursor = (int*)carve((size_t)NB_MAX * 4);
    int*   btot    = (int*)carve((size_t)NB_MAX * 4);
    float* dinv    = (float*)carve((size_t)n * 4);
    int*   flag    = (int*)carve(256);
    int*   offs    = (int*)carve((size_t)(n + 1) * 4);
    int*   cnt     = (int*)carve((size_t)n * 4);
    int*   partial = (int*)carve(4096);
    const size_t base = used;

    const size_t needT1 = base + 2 * A((size_t)E * 4) + 2 * A((size_t)n * HID * 4);
    const size_t needT2 = base + A((size_t)E * 4) + 2 * A((size_t)n * HID * 4);
    const size_t needT3 = base + 2 * A((size_t)n * HID * 4);
    const bool tier1 = (ws_size >= needT1) && (n <= 131071) && (nb <= NB_MAX);
    const bool tier2 = !tier1 && (ws_size >= needT2) && (n <= 131071);

    const int nblkN  = (n + 255) / 256;
    const int nblkEv = (int)((E + 256LL * EPT - 1) / (256LL * EPT));
    const int nblkSc = (n + SCAN_CHUNK - 1) / SCAN_CHUNK;
    const int nblkH  = (int)(((long long)n * HID + 255) / 256);
    const int nblkO  = (int)(((long long)n * OUT_CH + 255) / 256);

    detect_dtype<<<1, 64, 0, stream>>>(ei, E, n, flag);

    if (tier1) {
        int*   bucketed = (int*)carve((size_t)E * 4);
        int*   csr      = (int*)carve((size_t)E * 4);
        float* m1 = (float*)carve((size_t)n * HID * 4);
        float* h  = (float*)carve((size_t)n * HID * 4);
        float* m2 = m1;                            // m1 dead after agg1

        const long long chunk = (((E + FB_GRID - 1) / FB_GRID) + 3) & ~3LL;

        zero_int<<<(nb + 255) / 256, 256, 0, stream>>>(btot, nb);
        bucket_hist<<<FB_GRID, 256, 0, stream>>>(ei, E, flag, btot, nb, chunk);
        scan_buckets<<<1, 1024, 0, stream>>>(btot, bstart, bcursor, nb);
        fill_bucket<<<FB_GRID, 256, 0, stream>>>(ei, E, flag, bcursor, bucketed, nb, chunk);
        csr_sort<<<nb, 512, 0, stream>>>(bucketed, bstart, csr, offs, dinv, nb, n);

        gemm1p<<<(n + 7) / 8, 256, 0, stream>>>(x, W1, dinv, m1, n);
        agg1<<<(n + 7) / 8, 256, 0, stream>>>(m1, csr, offs, dinv, b1, h, n);
        gemm2p<<<nblkO, 256, 0, stream>>>(h, W2, dinv, m2, n);
        agg2<<<(n + 15) / 16, 256, 0, stream>>>(m2, csr, offs, dinv, b2, out, n);
    } else if (tier2) {
        int*   csr = (int*)carve((size_t)E * 4);
        float* m1  = (float*)carve((size_t)n * HID * 4);
        float* h   = (float*)carve((size_t)n * HID * 4);
        float* m2  = m1;

        zero_int<<<nblkN, 256, 0, stream>>>(cnt, n);
        count_edges<<<nblkEv, 256, 0, stream>>>(ei, cnt, E, flag);
        compute_dinv<<<nblkN, 256, 0, stream>>>(cnt, dinv, n);
        scan_partial<<<nblkSc, 256, 0, stream>>>(cnt, partial, n);
        scan_serial<<<1, 64, 0, stream>>>(partial, offs, nblkSc, n);
        scan_final<<<nblkSc, 256, 0, stream>>>(cnt, partial, offs, n);
        copy_int<<<nblkN, 256, 0, stream>>>(offs, cnt, n);

        const int npw = (n + NXCD - 1) / NXCD;
        fill_csr_win<<<nblkEv * NXCD, 256, 0, stream>>>(ei, cnt, csr, E, flag, npw, n);

        gemm1p<<<(n + 7) / 8, 256, 0, stream>>>(x, W1, dinv, m1, n);
        agg1<<<(n + 7) / 8, 256, 0, stream>>>(m1, csr, offs, dinv, b1, h, n);
        gemm2p<<<nblkO, 256, 0, stream>>>(h, W2, dinv, m2, n);
        agg2<<<(n + 15) / 16, 256, 0, stream>>>(m2, csr, offs, dinv, b2, out, n);
    } else if (ws_size >= needT3) {
        float* m1 = (float*)carve((size_t)n * HID * 4);
        float* h  = (float*)carve((size_t)n * HID * 4);
        float* m2 = m1;

        zero_int<<<nblkN, 256, 0, stream>>>(cnt, n);
        count_edges<<<nblkEv, 256, 0, stream>>>(ei, cnt, E, flag);
        compute_dinv<<<nblkN, 256, 0, stream>>>(cnt, dinv, n);

        gemm1p<<<(n + 7) / 8, 256, 0, stream>>>(x, W1, dinv, m1, n);
        zero_float<<<nblkH, 256, 0, stream>>>(h, (long long)n * HID);
        scatter1<<<(int)((E + 7) / 8), 256, 0, stream>>>(m1, ei, h, E, flag);
        fixup1<<<nblkH, 256, 0, stream>>>(m1, dinv, b1, h, n);
        gemm2p<<<nblkO, 256, 0, stream>>>(h, W2, dinv, m2, n);
        zero_float<<<nblkO, 256, 0, stream>>>(out, (long long)n * OUT_CH);
        scatter2<<<(int)((E + 15) / 16), 256, 0, stream>>>(m2, ei, out, E, flag);
        fixup2<<<nblkO, 256, 0, stream>>>(m2, dinv, b2, out, n);
    }
}

// Round 8
// 417.717 us; speedup vs baseline: 5.2975x; 1.0507x over previous
//
#include <hip/hip_runtime.h>
#include <hip/hip_bf16.h>

#define IN_CH 128
#define HID 32
#define OUT_CH 16
#define NPW 128           // nodes per bucket (col >> 7)
#define NPW_SHIFT 7
#define NB_MAX 1024
#define FB_GRID 256       // blocks in hist/fill
#define FB_THREADS 1024
#define CAP 12288         // LDS edge capacity in csr_sort (48 KB)
#define SCAN_CHUNK 1024
#define NXCD 8
#define EPT 4

typedef int vint4 __attribute__((ext_vector_type(4)));

// ---------------------------------------------------------------------------
__global__ void detect_dtype(const void* ei, long long ecount, int n, int* flag) {
    if (threadIdx.x == 0 && blockIdx.x == 0) {
        int is64 = 1;
        const long long* p = (const long long*)ei;
        long long st = ecount / 64; if (st < 1) st = 1;
        for (int j = 0; j < 64; ++j) {
            long long idx = (long long)j * st;
            if (idx >= ecount) break;
            long long v = p[idx];
            if (v < 0 || v >= n) { is64 = 0; break; }
        }
        *flag = is64;
    }
}

__device__ __forceinline__ int load_idx(const void* ei, long long i, int is64) {
    return is64 ? (int)((const long long*)ei)[i] : ((const int*)ei)[i];
}

__device__ __forceinline__ void load_idx4_nt(const void* ei, long long off, int is64,
                                             int* c) {
    if (is64) {
        const long long* p = (const long long*)ei + off;
        c[0] = (int)__builtin_nontemporal_load(p + 0);
        c[1] = (int)__builtin_nontemporal_load(p + 1);
        c[2] = (int)__builtin_nontemporal_load(p + 2);
        c[3] = (int)__builtin_nontemporal_load(p + 3);
    } else {
        vint4 v = __builtin_nontemporal_load((const vint4*)((const int*)ei + off));
        c[0] = v.x; c[1] = v.y; c[2] = v.z; c[3] = v.w;
    }
}

// ---------------------------------------------------------------------------
__global__ __launch_bounds__(256) void zero_int(int* p, int n) {
    int i = blockIdx.x * 256 + threadIdx.x;
    if (i < n) p[i] = 0;
}

__global__ __launch_bounds__(256) void zero_float(float* p, long long n) {
    long long i = (long long)blockIdx.x * 256 + threadIdx.x;
    if (i < n) p[i] = 0.f;
}

// ---------------------------------------------------------------------------
// pass A: per-block LDS histogram of its chunk -> bhist[bucket*FB_GRID+blk]
// (no global atomics at all)
// ---------------------------------------------------------------------------
__global__ __launch_bounds__(FB_THREADS) void bucket_hist(const void* ei, long long E,
                                                          const int* flag, int* bhist,
                                                          int nb, long long chunk) {
    __shared__ int hist[NB_MAX];
    for (int i = threadIdx.x; i < nb; i += FB_THREADS) hist[i] = 0;
    __syncthreads();
    long long lo = (long long)blockIdx.x * chunk;
    long long hi = lo + chunk; if (hi > E) hi = E;
    int is64 = *flag;
    if ((E & 3) == 0) {
        for (long long e = lo + (long long)threadIdx.x * EPT; e + EPT <= hi;
             e += (long long)FB_THREADS * EPT) {
            int c[4]; load_idx4_nt(ei, E + e, is64, c);
#pragma unroll
            for (int j = 0; j < 4; ++j) atomicAdd(&hist[c[j] >> NPW_SHIFT], 1);
        }
    } else {
        for (long long e = lo + threadIdx.x; e < hi; e += FB_THREADS)
            atomicAdd(&hist[load_idx(ei, E + e, is64) >> NPW_SHIFT], 1);
    }
    __syncthreads();
    for (int b = threadIdx.x; b < nb; b += FB_THREADS)
        bhist[b * FB_GRID + blockIdx.x] = hist[b];
}

// pass B: per-bucket exclusive scan over the FB_GRID block counts (in place)
// + bucket totals
__global__ __launch_bounds__(256) void scan_blocks(int* bhist, int* btot, int nb) {
    int b = blockIdx.x * 256 + threadIdx.x;
    if (b >= nb) return;
    int run = 0;
    int* p = bhist + (long long)b * FB_GRID;
    for (int j = 0; j < FB_GRID; ++j) { int v = p[j]; p[j] = run; run += v; }
    btot[b] = run;
}

// pass C: exclusive scan over nb (<= 2048) bucket totals, one block
__global__ __launch_bounds__(1024) void scan_buckets(const int* btot, int* bstart, int nb) {
    __shared__ int sd[1024];
    int t = threadIdx.x;
    int a0 = (2 * t < nb) ? btot[2 * t] : 0;
    int a1 = (2 * t + 1 < nb) ? btot[2 * t + 1] : 0;
    sd[t] = a0 + a1; __syncthreads();
    for (int off = 1; off < 1024; off <<= 1) {
        int v = (t >= off) ? sd[t - off] : 0;
        __syncthreads(); sd[t] += v; __syncthreads();
    }
    int excl = sd[t] - (a0 + a1);
    if (2 * t < nb)     bstart[2 * t] = excl;
    if (2 * t + 1 < nb) bstart[2 * t + 1] = excl + a0;
    if (t == 1023) bstart[nb] = sd[t];
}

// ---------------------------------------------------------------------------
// pass D: single-pass dense-write fill. Stage cur[b] = bstart[b]+bhist_excl,
// then stream edges once; LDS cursor atomics only; disjoint global ranges.
// ---------------------------------------------------------------------------
__global__ __launch_bounds__(FB_THREADS) void fill_bucket(const void* ei, long long E,
                                                          const int* flag,
                                                          const int* bhist,
                                                          const int* bstart,
                                                          int* bucketed, int nb,
                                                          long long chunk) {
    __shared__ int cur[NB_MAX];
    for (int b = threadIdx.x; b < nb; b += FB_THREADS)
        cur[b] = bstart[b] + bhist[b * FB_GRID + blockIdx.x];
    __syncthreads();
    long long lo = (long long)blockIdx.x * chunk;
    long long hi = lo + chunk; if (hi > E) hi = E;
    int is64 = *flag;
    if ((E & 3) == 0) {
        for (long long e = lo + (long long)threadIdx.x * EPT; e + EPT <= hi;
             e += (long long)FB_THREADS * EPT) {
            int c[4], r[4];
            load_idx4_nt(ei, E + e, is64, c);
            load_idx4_nt(ei, e, is64, r);
#pragma unroll
            for (int j = 0; j < 4; ++j) {
                int b = c[j] >> NPW_SHIFT;
                int pos = atomicAdd(&cur[b], 1);
                bucketed[pos] = r[j] | ((c[j] & (NPW - 1)) << 17);
            }
        }
    } else {
        for (long long e = lo + threadIdx.x; e < hi; e += FB_THREADS) {
            int col = load_idx(ei, E + e, is64);
            int row = load_idx(ei, e, is64);
            int b = col >> NPW_SHIFT;
            int pos = atomicAdd(&cur[b], 1);
            bucketed[pos] = row | ((col & (NPW - 1)) << 17);
        }
    }
}

// ---------------------------------------------------------------------------
// per-bucket node sort: LDS-stage bucket edges, NPW-node hist, serial scan,
// emit offs/dinv + node-sorted csr (rows only). All dense global IO.
// ---------------------------------------------------------------------------
__global__ __launch_bounds__(512) void csr_sort(const int* __restrict__ bucketed,
                                                const int* __restrict__ bstart,
                                                int* __restrict__ csr,
                                                int* __restrict__ offs,
                                                float* __restrict__ dinv,
                                                int nb, int n) {
    __shared__ int lds_e[CAP];
    __shared__ int hist[NPW];
    __shared__ int cur[NPW];
    int b = blockIdx.x, t = threadIdx.x;
    int s0 = bstart[b], s1 = bstart[b + 1];
    int cnt = s1 - s0;
    if (t < NPW) hist[t] = 0;
    __syncthreads();
    bool fit = (cnt <= CAP);
    if (fit) {
        for (int i = t; i < cnt; i += 512) {
            int e = bucketed[s0 + i];
            lds_e[i] = e;
            atomicAdd(&hist[e >> 17], 1);
        }
    } else {
        for (int i = t; i < cnt; i += 512)
            atomicAdd(&hist[bucketed[s0 + i] >> 17], 1);
    }
    __syncthreads();
    if (t == 0) {
        int run = 0;
        for (int k = 0; k < NPW; ++k) { cur[k] = run; run += hist[k]; }
    }
    __syncthreads();
    if (t < NPW) {
        int node = b * NPW + t;
        if (node < n) {
            offs[node] = s0 + cur[t];
            dinv[node] = 1.0f / sqrtf((float)(hist[t] + 1));  // +1 self loop
        }
    }
    if (b == nb - 1 && t == 0) offs[n] = s1;
    __syncthreads();
    if (fit) {
        for (int i = t; i < cnt; i += 512) {
            int e = lds_e[i];
            int pos = atomicAdd(&cur[e >> 17], 1);
            csr[s0 + pos] = e & 0x1FFFF;
        }
    } else {
        for (int i = t; i < cnt; i += 512) {
            int e = bucketed[s0 + i];
            int pos = atomicAdd(&cur[e >> 17], 1);
            csr[s0 + pos] = e & 0x1FFFF;
        }
    }
}

// ---------------------------------------------------------------------------
// GEMMs with dinv pre-multiplied (kills per-edge dinv gather in agg)
// ---------------------------------------------------------------------------
__global__ __launch_bounds__(256) void gemm1p(const float* __restrict__ x,
                                              const float* __restrict__ W1,
                                              const float* __restrict__ dinv,
                                              float* __restrict__ m1, int n) {
    __shared__ float sW[IN_CH * HID];
    __shared__ float sx[8][IN_CH];
    for (int i = threadIdx.x; i < IN_CH * HID; i += 256) sW[i] = W1[i];
    int g = threadIdx.x >> 5;
    int c = threadIdx.x & 31;
    long long node = (long long)blockIdx.x * 8 + g;
    bool active = node < n;
    if (active) {
        const float4* xr = (const float4*)(x + node * IN_CH);
        float4 v = xr[c];
        sx[g][c * 4 + 0] = v.x; sx[g][c * 4 + 1] = v.y;
        sx[g][c * 4 + 2] = v.z; sx[g][c * 4 + 3] = v.w;
    }
    __syncthreads();
    if (!active) return;
    float acc = 0.f;
#pragma unroll
    for (int k = 0; k < IN_CH; ++k)
        acc = fmaf(sx[g][k], sW[k * HID + c], acc);
    m1[node * HID + c] = acc * dinv[node];
}

__global__ __launch_bounds__(256) void gemm2p(const float* __restrict__ h,
                                              const float* __restrict__ W2,
                                              const float* __restrict__ dinv,
                                              float* __restrict__ m2, int n) {
    __shared__ float sW[HID * OUT_CH];
    for (int i = threadIdx.x; i < HID * OUT_CH; i += 256) sW[i] = W2[i];
    __syncthreads();
    long long t = (long long)blockIdx.x * 256 + threadIdx.x;
    long long node = t >> 4;
    int c = (int)(t & 15);
    if (node >= n) return;
    const float* hr = h + node * HID;
    float acc = 0.f;
#pragma unroll
    for (int k = 0; k < HID; ++k)
        acc = fmaf(hr[k], sW[k * OUT_CH + c], acc);
    m2[node * OUT_CH + c] = acc * dinv[node];
}

// ---------------------------------------------------------------------------
// CSR gather aggregation (high parallelism; m pre-scaled -> no dinv gather)
// ---------------------------------------------------------------------------
__global__ __launch_bounds__(256) void agg1(const float* __restrict__ m1s,
                                            const int* __restrict__ csr,
                                            const int* __restrict__ offs,
                                            const float* __restrict__ dinv,
                                            const float* __restrict__ b1,
                                            float* __restrict__ h, int n) {
    int g = threadIdx.x >> 5;
    int c = threadIdx.x & 31;
    long long node = (long long)blockIdx.x * 8 + g;
    if (node >= n) return;
    float acc = m1s[(node << 5) + c];      // self loop
    int s = offs[node], e1 = offs[node + 1];
    for (; s + 3 < e1; s += 4) {
        int s0 = csr[s], s1 = csr[s + 1], s2 = csr[s + 2], s3 = csr[s + 3];
        float v0 = m1s[((long long)s0 << 5) + c];
        float v1 = m1s[((long long)s1 << 5) + c];
        float v2 = m1s[((long long)s2 << 5) + c];
        float v3 = m1s[((long long)s3 << 5) + c];
        acc += v0; acc += v1; acc += v2; acc += v3;
    }
    for (; s < e1; ++s) acc += m1s[((long long)csr[s] << 5) + c];
    float val = acc * dinv[node] + b1[c];
    h[(node << 5) + c] = val > 0.f ? val : 0.f;
}

__global__ __launch_bounds__(256) void agg2(const float* __restrict__ m2s,
                                            const int* __restrict__ csr,
                                            const int* __restrict__ offs,
                                            const float* __restrict__ dinv,
                                            const float* __restrict__ b2,
                                            float* __restrict__ out, int n) {
    int g = threadIdx.x >> 4;
    int c = threadIdx.x & 15;
    long long node = (long long)blockIdx.x * 16 + g;
    if (node >= n) return;
    float acc = m2s[(node << 4) + c];
    int s = offs[node], e1 = offs[node + 1];
    for (; s + 3 < e1; s += 4) {
        int s0 = csr[s], s1 = csr[s + 1], s2 = csr[s + 2], s3 = csr[s + 3];
        float v0 = m2s[((long long)s0 << 4) + c];
        float v1 = m2s[((long long)s1 << 4) + c];
        float v2 = m2s[((long long)s2 << 4) + c];
        float v3 = m2s[((long long)s3 << 4) + c];
        acc += v0; acc += v1; acc += v2; acc += v3;
    }
    for (; s < e1; ++s) acc += m2s[((long long)csr[s] << 4) + c];
    out[(node << 4) + c] = acc * dinv[node] + b2[c];
}

// ---------------------------------------------------------------------------
// tier 2: windowed CSR fill path
// ---------------------------------------------------------------------------
__global__ __launch_bounds__(256) void count_edges(const void* ei, int* cnt,
                                                   long long E, const int* flag) {
    long long e0 = ((long long)blockIdx.x * 256 + threadIdx.x) * EPT;
    if (e0 >= E) return;
    int is64 = *flag;
    if (e0 + EPT <= E && (E & 3) == 0) {
        int c[EPT];
        load_idx4_nt(ei, E + e0, is64, c);
#pragma unroll
        for (int j = 0; j < EPT; ++j) atomicAdd(&cnt[c[j]], 1);
    } else {
        for (long long e = e0; e < E && e < e0 + EPT; ++e)
            atomicAdd(&cnt[load_idx(ei, E + e, is64)], 1);
    }
}

__global__ __launch_bounds__(256) void compute_dinv(const int* cnt, float* dinv, int n) {
    int i = blockIdx.x * 256 + threadIdx.x;
    if (i < n) dinv[i] = 1.0f / sqrtf((float)(cnt[i] + 1));
}

__global__ __launch_bounds__(256) void scan_partial(const int* cnt, int* partial, int n) {
    __shared__ int sd[256];
    int base = blockIdx.x * SCAN_CHUNK;
    int s = 0;
    for (int j = threadIdx.x; j < SCAN_CHUNK; j += 256) {
        int i = base + j;
        if (i < n) s += cnt[i];
    }
    sd[threadIdx.x] = s;
    __syncthreads();
    for (int off = 128; off > 0; off >>= 1) {
        if (threadIdx.x < off) sd[threadIdx.x] += sd[threadIdx.x + off];
        __syncthreads();
    }
    if (threadIdx.x == 0) partial[blockIdx.x] = sd[0];
}

__global__ void scan_serial(int* partial, int* offs, int nblk, int n) {
    if (threadIdx.x == 0 && blockIdx.x == 0) {
        int run = 0;
        for (int b = 0; b < nblk; ++b) { int t = partial[b]; partial[b] = run; run += t; }
        offs[n] = run;
    }
}

__global__ __launch_bounds__(256) void scan_final(const int* cnt, const int* partial,
                                                  int* offs, int n) {
    __shared__ int sd[256];
    int base = blockIdx.x * SCAN_CHUNK;
    int t = threadIdx.x;
    int loc[4]; int ts = 0;
#pragma unroll
    for (int j = 0; j < 4; ++j) {
        int i = base + t * 4 + j;
        loc[j] = (i < n) ? cnt[i] : 0;
        ts += loc[j];
    }
    sd[t] = ts;
    __syncthreads();
    for (int off = 1; off < 256; off <<= 1) {
        int v = (t >= off) ? sd[t - off] : 0;
        __syncthreads();
        sd[t] += v;
        __syncthreads();
    }
    int excl = sd[t] - ts + partial[blockIdx.x];
#pragma unroll
    for (int j = 0; j < 4; ++j) {
        int i = base + t * 4 + j;
        if (i < n) offs[i] = excl;
        excl += loc[j];
    }
}

__global__ __launch_bounds__(256) void copy_int(const int* src, int* dst, int n) {
    int i = blockIdx.x * 256 + threadIdx.x;
    if (i < n) dst[i] = src[i];
}

__global__ __launch_bounds__(256) void fill_csr_win(const void* ei, int* cursor, int* csr,
                                                    long long E, const int* flag,
                                                    int npw, int n) {
    int w = blockIdx.x & (NXCD - 1);
    int b = blockIdx.x >> 3;
    int lo = w * npw;
    int hi = lo + npw; if (hi > n) hi = n;
    long long e0 = ((long long)b * 256 + threadIdx.x) * EPT;
    if (e0 >= E) return;
    int is64 = *flag;
    if (e0 + EPT <= E && (E & 3) == 0) {
        int c[EPT];
        load_idx4_nt(ei, E + e0, is64, c);
#pragma unroll
        for (int j = 0; j < EPT; ++j) {
            if (c[j] >= lo && c[j] < hi) {
                int row = load_idx(ei, e0 + j, is64);
                int pos = atomicAdd(&cursor[c[j]], 1);
                csr[pos] = row;
            }
        }
    } else {
        for (long long e = e0; e < E && e < e0 + EPT; ++e) {
            int col = load_idx(ei, E + e, is64);
            if (col >= lo && col < hi) {
                int row = load_idx(ei, e, is64);
                int pos = atomicAdd(&cursor[col], 1);
                csr[pos] = row;
            }
        }
    }
}

// ---------------------------------------------------------------------------
// tier 3: scatter fallback (m pre-scaled)
// ---------------------------------------------------------------------------
__global__ __launch_bounds__(256) void scatter1(const float* __restrict__ m1s,
                                                const void* ei,
                                                float* __restrict__ h,
                                                long long E, const int* flag) {
    long long e = (long long)blockIdx.x * 8 + (threadIdx.x >> 5);
    int c = threadIdx.x & 31;
    if (e >= E) return;
    int is64 = *flag;
    int row = load_idx(ei, e, is64);
    int col = load_idx(ei, E + e, is64);
    atomicAdd(&h[(long long)col * HID + c], m1s[(long long)row * HID + c]);
}

__global__ __launch_bounds__(256) void fixup1(const float* __restrict__ m1s,
                                              const float* __restrict__ dinv,
                                              const float* __restrict__ b1,
                                              float* __restrict__ h, int n) {
    long long t = (long long)blockIdx.x * 256 + threadIdx.x;
    long long node = t >> 5; int c = (int)(t & 31);
    if (node >= n) return;
    float v = (h[node * HID + c] + m1s[node * HID + c]) * dinv[node] + b1[c];
    h[node * HID + c] = v > 0.f ? v : 0.f;
}

__global__ __launch_bounds__(256) void scatter2(const float* __restrict__ m2s,
                                                const void* ei,
                                                float* __restrict__ out,
                                                long long E, const int* flag) {
    long long e = (long long)blockIdx.x * 16 + (threadIdx.x >> 4);
    int c = threadIdx.x & 15;
    if (e >= E) return;
    int is64 = *flag;
    int row = load_idx(ei, e, is64);
    int col = load_idx(ei, E + e, is64);
    atomicAdd(&out[(long long)col * OUT_CH + c], m2s[(long long)row * OUT_CH + c]);
}

__global__ __launch_bounds__(256) void fixup2(const float* __restrict__ m2s,
                                              const float* __restrict__ dinv,
                                              const float* __restrict__ b2,
                                              float* __restrict__ out, int n) {
    long long t = (long long)blockIdx.x * 256 + threadIdx.x;
    long long node = t >> 4; int c = (int)(t & 15);
    if (node >= n) return;
    out[node * OUT_CH + c] = (out[node * OUT_CH + c] + m2s[node * OUT_CH + c]) * dinv[node] + b2[c];
}

// ---------------------------------------------------------------------------
extern "C" void kernel_launch(void* const* d_in, const int* in_sizes, int n_in,
                              void* d_out, int out_size, void* d_ws, size_t ws_size,
                              hipStream_t stream) {
    const float* x  = (const float*)d_in[0];
    const void*  ei = d_in[1];
    const float* W1 = (const float*)d_in[2];
    const float* b1 = (const float*)d_in[3];
    const float* W2 = (const float*)d_in[4];
    const float* b2 = (const float*)d_in[5];
    float* out = (float*)d_out;

    const int n = in_sizes[0] / IN_CH;           // 100000
    const long long E = in_sizes[1] / 2;         // 6400000
    const int nb = (n + NPW - 1) / NPW;          // 782

    char* w = (char*)d_ws;
    size_t used = 0;
    auto carve = [&](size_t bytes) -> void* {
        void* p = (void*)(w + used);
        used += (bytes + 255) & ~(size_t)255;
        return p;
    };
    auto A = [](size_t b) -> size_t { return (b + 255) & ~(size_t)255; };

    int*   bstart  = (int*)carve((size_t)(NB_MAX + 1) * 4);
    int*   btot    = (int*)carve((size_t)NB_MAX * 4);
    float* dinv    = (float*)carve((size_t)n * 4);
    int*   flag    = (int*)carve(256);
    int*   offs    = (int*)carve((size_t)(n + 1) * 4);
    int*   cnt     = (int*)carve((size_t)n * 4);
    int*   partial = (int*)carve(4096);
    const size_t base = used;

    const size_t bhistB = A((size_t)nb * FB_GRID * 4);
    const size_t needT1 = base + bhistB + 2 * A((size_t)E * 4) + 2 * A((size_t)n * HID * 4);
    const size_t needT2 = base + A((size_t)E * 4) + 2 * A((size_t)n * HID * 4);
    const size_t needT3 = base + 2 * A((size_t)n * HID * 4);
    const bool tier1 = (ws_size >= needT1) && (n <= 131071) && (nb <= NB_MAX);
    const bool tier2 = !tier1 && (ws_size >= needT2) && (n <= 131071);

    const int nblkN  = (n + 255) / 256;
    const int nblkEv = (int)((E + 256LL * EPT - 1) / (256LL * EPT));
    const int nblkSc = (n + SCAN_CHUNK - 1) / SCAN_CHUNK;
    const int nblkH  = (int)(((long long)n * HID + 255) / 256);
    const int nblkO  = (int)(((long long)n * OUT_CH + 255) / 256);

    detect_dtype<<<1, 64, 0, stream>>>(ei, E, n, flag);

    if (tier1) {
        int*   bhist    = (int*)carve((size_t)nb * FB_GRID * 4);
        int*   bucketed = (int*)carve((size_t)E * 4);
        int*   csr      = (int*)carve((size_t)E * 4);
        float* m1 = (float*)carve((size_t)n * HID * 4);
        float* h  = (float*)carve((size_t)n * HID * 4);
        float* m2 = m1;                            // m1 dead after agg1

        const long long chunk = (((E + FB_GRID - 1) / FB_GRID) + 3) & ~3LL;

        bucket_hist<<<FB_GRID, FB_THREADS, 0, stream>>>(ei, E, flag, bhist, nb, chunk);
        scan_blocks<<<(nb + 255) / 256, 256, 0, stream>>>(bhist, btot, nb);
        scan_buckets<<<1, 1024, 0, stream>>>(btot, bstart, nb);
        fill_bucket<<<FB_GRID, FB_THREADS, 0, stream>>>(ei, E, flag, bhist, bstart,
                                                        bucketed, nb, chunk);
        csr_sort<<<nb, 512, 0, stream>>>(bucketed, bstart, csr, offs, dinv, nb, n);

        gemm1p<<<(n + 7) / 8, 256, 0, stream>>>(x, W1, dinv, m1, n);
        agg1<<<(n + 7) / 8, 256, 0, stream>>>(m1, csr, offs, dinv, b1, h, n);
        gemm2p<<<nblkO, 256, 0, stream>>>(h, W2, dinv, m2, n);
        agg2<<<(n + 15) / 16, 256, 0, stream>>>(m2, csr, offs, dinv, b2, out, n);
    } else if (tier2) {
        int*   csr = (int*)carve((size_t)E * 4);
        float* m1  = (float*)carve((size_t)n * HID * 4);
        float* h   = (float*)carve((size_t)n * HID * 4);
        float* m2  = m1;

        zero_int<<<nblkN, 256, 0, stream>>>(cnt, n);
        count_edges<<<nblkEv, 256, 0, stream>>>(ei, cnt, E, flag);
        compute_dinv<<<nblkN, 256, 0, stream>>>(cnt, dinv, n);
        scan_partial<<<nblkSc, 256, 0, stream>>>(cnt, partial, n);
        scan_serial<<<1, 64, 0, stream>>>(partial, offs, nblkSc, n);
        scan_final<<<nblkSc, 256, 0, stream>>>(cnt, partial, offs, n);
        copy_int<<<nblkN, 256, 0, stream>>>(offs, cnt, n);

        const int npw2 = (n + NXCD - 1) / NXCD;
        fill_csr_win<<<nblkEv * NXCD, 256, 0, stream>>>(ei, cnt, csr, E, flag, npw2, n);

        gemm1p<<<(n + 7) / 8, 256, 0, stream>>>(x, W1, dinv, m1, n);
        agg1<<<(n + 7) / 8, 256, 0, stream>>>(m1, csr, offs, dinv, b1, h, n);
        gemm2p<<<nblkO, 256, 0, stream>>>(h, W2, dinv, m2, n);
        agg2<<<(n + 15) / 16, 256, 0, stream>>>(m2, csr, offs, dinv, b2, out, n);
    } else if (ws_size >= needT3) {
        float* m1 = (float*)carve((size_t)n * HID * 4);
        float* h  = (float*)carve((size_t)n * HID * 4);
        float* m2 = m1;

        zero_int<<<nblkN, 256, 0, stream>>>(cnt, n);
        count_edges<<<nblkEv, 256, 0, stream>>>(ei, cnt, E, flag);
        compute_dinv<<<nblkN, 256, 0, stream>>>(cnt, dinv, n);

        gemm1p<<<(n + 7) / 8, 256, 0, stream>>>(x, W1, dinv, m1, n);
        zero_float<<<nblkH, 256, 0, stream>>>(h, (long long)n * HID);
        scatter1<<<(int)((E + 7) / 8), 256, 0, stream>>>(m1, ei, h, E, flag);
        fixup1<<<nblkH, 256, 0, stream>>>(m1, dinv, b1, h, n);
        gemm2p<<<nblkO, 256, 0, stream>>>(h, W2, dinv, m2, n);
        zero_float<<<nblkO, 256, 0, stream>>>(out, (long long)n * OUT_CH);
        scatter2<<<(int)((E + 15) / 16), 256, 0, stream>>>(m2, ei, out, E, flag);
        fixup2<<<nblkO, 256, 0, stream>>>(m2, dinv, b2, out, n);
    }
}

// Round 9
// 358.068 us; speedup vs baseline: 6.1799x; 1.1666x over previous
//
#include <hip/hip_runtime.h>
#include <hip/hip_bf16.h>

#define IN_CH 128
#define HID 32
#define OUT_CH 16
#define NPW 128           // nodes per bucket (col >> 7)
#define NPW_SHIFT 7
#define NB_MAX 1024
#define FB_GRID 256       // blocks in hist/fill
#define FB_THREADS 1024
#define CAP 12288         // LDS edge capacity in csr_sort (48 KB)
#define SCAN_CHUNK 1024
#define NXCD 8
#define EPT 8

typedef int vint4 __attribute__((ext_vector_type(4)));
typedef vint4 vint4u __attribute__((aligned(4)));   // unaligned-ok vector load

// ---------------------------------------------------------------------------
__global__ void detect_dtype(const void* ei, long long ecount, int n, int* flag) {
    if (threadIdx.x == 0 && blockIdx.x == 0) {
        int is64 = 1;
        const long long* p = (const long long*)ei;
        long long st = ecount / 64; if (st < 1) st = 1;
        for (int j = 0; j < 64; ++j) {
            long long idx = (long long)j * st;
            if (idx >= ecount) break;
            long long v = p[idx];
            if (v < 0 || v >= n) { is64 = 0; break; }
        }
        *flag = is64;
    }
}

__device__ __forceinline__ int load_idx(const void* ei, long long i, int is64) {
    return is64 ? (int)((const long long*)ei)[i] : ((const int*)ei)[i];
}

// 8 consecutive indices, nontemporal; offset must be 8-element aligned
__device__ __forceinline__ void load_idx8_nt(const void* ei, long long off, int is64,
                                             int* c) {
    if (is64) {
        const long long* p = (const long long*)ei + off;
#pragma unroll
        for (int j = 0; j < 8; ++j) c[j] = (int)__builtin_nontemporal_load(p + j);
    } else {
        vint4 v0 = __builtin_nontemporal_load((const vint4*)((const int*)ei + off));
        vint4 v1 = __builtin_nontemporal_load((const vint4*)((const int*)ei + off + 4));
        c[0] = v0.x; c[1] = v0.y; c[2] = v0.z; c[3] = v0.w;
        c[4] = v1.x; c[5] = v1.y; c[6] = v1.z; c[7] = v1.w;
    }
}

// ---------------------------------------------------------------------------
__global__ __launch_bounds__(256) void zero_int(int* p, int n) {
    int i = blockIdx.x * 256 + threadIdx.x;
    if (i < n) p[i] = 0;
}

__global__ __launch_bounds__(256) void zero_float(float* p, long long n) {
    long long i = (long long)blockIdx.x * 256 + threadIdx.x;
    if (i < n) p[i] = 0.f;
}

// ---------------------------------------------------------------------------
// pass A: per-block LDS histogram of its chunk -> bhist[bucket*FB_GRID+blk]
// ---------------------------------------------------------------------------
__global__ __launch_bounds__(FB_THREADS) void bucket_hist(const void* ei, long long E,
                                                          const int* flag, int* bhist,
                                                          int nb, long long chunk) {
    __shared__ int hist[NB_MAX];
    for (int i = threadIdx.x; i < nb; i += FB_THREADS) hist[i] = 0;
    __syncthreads();
    long long lo = (long long)blockIdx.x * chunk;
    long long hi = lo + chunk; if (hi > E) hi = E;
    int is64 = *flag;
    if ((E & 7) == 0) {
        for (long long e = lo + (long long)threadIdx.x * EPT; e + EPT <= hi;
             e += (long long)FB_THREADS * EPT) {
            int c[8]; load_idx8_nt(ei, E + e, is64, c);
#pragma unroll
            for (int j = 0; j < 8; ++j) atomicAdd(&hist[c[j] >> NPW_SHIFT], 1);
        }
    } else {
        for (long long e = lo + threadIdx.x; e < hi; e += FB_THREADS)
            atomicAdd(&hist[load_idx(ei, E + e, is64) >> NPW_SHIFT], 1);
    }
    __syncthreads();
    for (int b = threadIdx.x; b < nb; b += FB_THREADS)
        bhist[b * FB_GRID + blockIdx.x] = hist[b];
}

// pass B: per-bucket exclusive scan over FB_GRID block counts (one block/bucket,
// coalesced LDS scan) + bucket totals
__global__ __launch_bounds__(256) void scan_blocks(int* bhist, int* btot, int nb) {
    __shared__ int sd[FB_GRID];
    int b = blockIdx.x, t = threadIdx.x;
    int* p = bhist + (long long)b * FB_GRID;
    int v = p[t];
    sd[t] = v; __syncthreads();
    for (int off = 1; off < FB_GRID; off <<= 1) {
        int u = (t >= off) ? sd[t - off] : 0;
        __syncthreads(); sd[t] += u; __syncthreads();
    }
    p[t] = sd[t] - v;                 // exclusive
    if (t == FB_GRID - 1) btot[b] = sd[t];
}

// pass C: exclusive scan over nb (<= 2048) bucket totals, one block
__global__ __launch_bounds__(1024) void scan_buckets(const int* btot, int* bstart, int nb) {
    __shared__ int sd[1024];
    int t = threadIdx.x;
    int a0 = (2 * t < nb) ? btot[2 * t] : 0;
    int a1 = (2 * t + 1 < nb) ? btot[2 * t + 1] : 0;
    sd[t] = a0 + a1; __syncthreads();
    for (int off = 1; off < 1024; off <<= 1) {
        int v = (t >= off) ? sd[t - off] : 0;
        __syncthreads(); sd[t] += v; __syncthreads();
    }
    int excl = sd[t] - (a0 + a1);
    if (2 * t < nb)     bstart[2 * t] = excl;
    if (2 * t + 1 < nb) bstart[2 * t + 1] = excl + a0;
    if (t == 1023) bstart[nb] = sd[t];
}

// ---------------------------------------------------------------------------
// pass D: single-pass dense-write fill (LDS cursors, disjoint global ranges)
// ---------------------------------------------------------------------------
__global__ __launch_bounds__(FB_THREADS) void fill_bucket(const void* ei, long long E,
                                                          const int* flag,
                                                          const int* bhist,
                                                          const int* bstart,
                                                          int* bucketed, int nb,
                                                          long long chunk) {
    __shared__ int cur[NB_MAX];
    for (int b = threadIdx.x; b < nb; b += FB_THREADS)
        cur[b] = bstart[b] + bhist[b * FB_GRID + blockIdx.x];
    __syncthreads();
    long long lo = (long long)blockIdx.x * chunk;
    long long hi = lo + chunk; if (hi > E) hi = E;
    int is64 = *flag;
    if ((E & 7) == 0) {
        for (long long e = lo + (long long)threadIdx.x * EPT; e + EPT <= hi;
             e += (long long)FB_THREADS * EPT) {
            int c[8], r[8];
            load_idx8_nt(ei, E + e, is64, c);
            load_idx8_nt(ei, e, is64, r);
#pragma unroll
            for (int j = 0; j < 8; ++j) {
                int b = c[j] >> NPW_SHIFT;
                int pos = atomicAdd(&cur[b], 1);
                bucketed[pos] = r[j] | ((c[j] & (NPW - 1)) << 17);
            }
        }
    } else {
        for (long long e = lo + threadIdx.x; e < hi; e += FB_THREADS) {
            int col = load_idx(ei, E + e, is64);
            int row = load_idx(ei, e, is64);
            int b = col >> NPW_SHIFT;
            int pos = atomicAdd(&cur[b], 1);
            bucketed[pos] = row | ((col & (NPW - 1)) << 17);
        }
    }
}

// ---------------------------------------------------------------------------
// per-bucket node sort: LDS-stage bucket edges, NPW-node hist, serial scan,
// emit offs/dinv + node-sorted csr (rows only).
// ---------------------------------------------------------------------------
__global__ __launch_bounds__(512) void csr_sort(const int* __restrict__ bucketed,
                                                const int* __restrict__ bstart,
                                                int* __restrict__ csr,
                                                int* __restrict__ offs,
                                                float* __restrict__ dinv,
                                                int nb, int n) {
    __shared__ int lds_e[CAP];
    __shared__ int hist[NPW];
    __shared__ int cur[NPW];
    int b = blockIdx.x, t = threadIdx.x;
    int s0 = bstart[b], s1 = bstart[b + 1];
    int cnt = s1 - s0;
    if (t < NPW) hist[t] = 0;
    __syncthreads();
    bool fit = (cnt <= CAP);
    int cnt4 = cnt & ~3;
    if (fit) {
        for (int i = t * 4; i < cnt4; i += 2048) {
            vint4u e4 = *(const vint4u*)(bucketed + s0 + i);
            lds_e[i + 0] = e4.x; atomicAdd(&hist[e4.x >> 17], 1);
            lds_e[i + 1] = e4.y; atomicAdd(&hist[e4.y >> 17], 1);
            lds_e[i + 2] = e4.z; atomicAdd(&hist[e4.z >> 17], 1);
            lds_e[i + 3] = e4.w; atomicAdd(&hist[e4.w >> 17], 1);
        }
        for (int i = cnt4 + t; i < cnt; i += 512) {
            int e = bucketed[s0 + i];
            lds_e[i] = e;
            atomicAdd(&hist[e >> 17], 1);
        }
    } else {
        for (int i = t * 4; i < cnt4; i += 2048) {
            vint4u e4 = *(const vint4u*)(bucketed + s0 + i);
            atomicAdd(&hist[e4.x >> 17], 1);
            atomicAdd(&hist[e4.y >> 17], 1);
            atomicAdd(&hist[e4.z >> 17], 1);
            atomicAdd(&hist[e4.w >> 17], 1);
        }
        for (int i = cnt4 + t; i < cnt; i += 512)
            atomicAdd(&hist[bucketed[s0 + i] >> 17], 1);
    }
    __syncthreads();
    if (t == 0) {
        int run = 0;
        for (int k = 0; k < NPW; ++k) { cur[k] = run; run += hist[k]; }
    }
    __syncthreads();
    if (t < NPW) {
        int node = b * NPW + t;
        if (node < n) {
            offs[node] = s0 + cur[t];
            dinv[node] = 1.0f / sqrtf((float)(hist[t] + 1));  // +1 self loop
        }
    }
    if (b == nb - 1 && t == 0) offs[n] = s1;
    __syncthreads();
    if (fit) {
        for (int i = t; i < cnt; i += 512) {
            int e = lds_e[i];
            int pos = atomicAdd(&cur[e >> 17], 1);
            csr[s0 + pos] = e & 0x1FFFF;
        }
    } else {
        for (int i = t; i < cnt; i += 512) {
            int e = bucketed[s0 + i];
            int pos = atomicAdd(&cur[e >> 17], 1);
            csr[s0 + pos] = e & 0x1FFFF;
        }
    }
}

// ---------------------------------------------------------------------------
// GEMMs with dinv pre-multiplied (kills per-edge dinv gather in agg)
// ---------------------------------------------------------------------------
__global__ __launch_bounds__(256) void gemm1p(const float* __restrict__ x,
                                              const float* __restrict__ W1,
                                              const float* __restrict__ dinv,
                                              float* __restrict__ m1, int n) {
    __shared__ float sW[IN_CH * HID];
    __shared__ float sx[8][IN_CH];
    for (int i = threadIdx.x; i < IN_CH * HID; i += 256) sW[i] = W1[i];
    int g = threadIdx.x >> 5;
    int c = threadIdx.x & 31;
    long long node = (long long)blockIdx.x * 8 + g;
    bool active = node < n;
    if (active) {
        const float4* xr = (const float4*)(x + node * IN_CH);
        float4 v = xr[c];
        sx[g][c * 4 + 0] = v.x; sx[g][c * 4 + 1] = v.y;
        sx[g][c * 4 + 2] = v.z; sx[g][c * 4 + 3] = v.w;
    }
    __syncthreads();
    if (!active) return;
    float acc = 0.f;
#pragma unroll
    for (int k = 0; k < IN_CH; ++k)
        acc = fmaf(sx[g][k], sW[k * HID + c], acc);
    m1[node * HID + c] = acc * dinv[node];
}

__global__ __launch_bounds__(256) void gemm2p(const float* __restrict__ h,
                                              const float* __restrict__ W2,
                                              const float* __restrict__ dinv,
                                              float* __restrict__ m2, int n) {
    __shared__ float sW[HID * OUT_CH];
    for (int i = threadIdx.x; i < HID * OUT_CH; i += 256) sW[i] = W2[i];
    __syncthreads();
    long long t = (long long)blockIdx.x * 256 + threadIdx.x;
    long long node = t >> 4;
    int c = (int)(t & 15);
    if (node >= n) return;
    const float* hr = h + node * HID;
    float acc = 0.f;
#pragma unroll
    for (int k = 0; k < HID; ++k)
        acc = fmaf(hr[k], sW[k * OUT_CH + c], acc);
    m2[node * OUT_CH + c] = acc * dinv[node];
}

// ---------------------------------------------------------------------------
// CSR gather aggregation: 8-wide unroll, csr batch via 2 broadcast dwordx4
// ---------------------------------------------------------------------------
__global__ __launch_bounds__(256) void agg1(const float* __restrict__ m1s,
                                            const int* __restrict__ csr,
                                            const int* __restrict__ offs,
                                            const float* __restrict__ dinv,
                                            const float* __restrict__ b1,
                                            float* __restrict__ h, int n) {
    int g = threadIdx.x >> 5;
    int c = threadIdx.x & 31;
    long long node = (long long)blockIdx.x * 8 + g;
    if (node >= n) return;
    float acc = m1s[(node << 5) + c];      // self loop
    int s = offs[node], e1 = offs[node + 1];
    for (; s + 7 < e1; s += 8) {
        vint4u a = *(const vint4u*)(csr + s);
        vint4u b = *(const vint4u*)(csr + s + 4);
        float v0 = m1s[((long long)a.x << 5) + c];
        float v1 = m1s[((long long)a.y << 5) + c];
        float v2 = m1s[((long long)a.z << 5) + c];
        float v3 = m1s[((long long)a.w << 5) + c];
        float v4 = m1s[((long long)b.x << 5) + c];
        float v5 = m1s[((long long)b.y << 5) + c];
        float v6 = m1s[((long long)b.z << 5) + c];
        float v7 = m1s[((long long)b.w << 5) + c];
        acc += v0; acc += v1; acc += v2; acc += v3;
        acc += v4; acc += v5; acc += v6; acc += v7;
    }
    for (; s < e1; ++s) acc += m1s[((long long)csr[s] << 5) + c];
    float val = acc * dinv[node] + b1[c];
    h[(node << 5) + c] = val > 0.f ? val : 0.f;
}

__global__ __launch_bounds__(256) void agg2(const float* __restrict__ m2s,
                                            const int* __restrict__ csr,
                                            const int* __restrict__ offs,
                                            const float* __restrict__ dinv,
                                            const float* __restrict__ b2,
                                            float* __restrict__ out, int n) {
    int g = threadIdx.x >> 4;
    int c = threadIdx.x & 15;
    long long node = (long long)blockIdx.x * 16 + g;
    if (node >= n) return;
    float acc = m2s[(node << 4) + c];
    int s = offs[node], e1 = offs[node + 1];
    for (; s + 7 < e1; s += 8) {
        vint4u a = *(const vint4u*)(csr + s);
        vint4u b = *(const vint4u*)(csr + s + 4);
        float v0 = m2s[((long long)a.x << 4) + c];
        float v1 = m2s[((long long)a.y << 4) + c];
        float v2 = m2s[((long long)a.z << 4) + c];
        float v3 = m2s[((long long)a.w << 4) + c];
        float v4 = m2s[((long long)b.x << 4) + c];
        float v5 = m2s[((long long)b.y << 4) + c];
        float v6 = m2s[((long long)b.z << 4) + c];
        float v7 = m2s[((long long)b.w << 4) + c];
        acc += v0; acc += v1; acc += v2; acc += v3;
        acc += v4; acc += v5; acc += v6; acc += v7;
    }
    for (; s < e1; ++s) acc += m2s[((long long)csr[s] << 4) + c];
    out[(node << 4) + c] = acc * dinv[node] + b2[c];
}

// ---------------------------------------------------------------------------
// tier 2: windowed CSR fill path
// ---------------------------------------------------------------------------
__global__ __launch_bounds__(256) void count_edges(const void* ei, int* cnt,
                                                   long long E, const int* flag) {
    long long e0 = ((long long)blockIdx.x * 256 + threadIdx.x) * EPT;
    if (e0 >= E) return;
    int is64 = *flag;
    if (e0 + EPT <= E && (E & 7) == 0) {
        int c[EPT];
        load_idx8_nt(ei, E + e0, is64, c);
#pragma unroll
        for (int j = 0; j < EPT; ++j) atomicAdd(&cnt[c[j]], 1);
    } else {
        for (long long e = e0; e < E && e < e0 + EPT; ++e)
            atomicAdd(&cnt[load_idx(ei, E + e, is64)], 1);
    }
}

__global__ __launch_bounds__(256) void compute_dinv(const int* cnt, float* dinv, int n) {
    int i = blockIdx.x * 256 + threadIdx.x;
    if (i < n) dinv[i] = 1.0f / sqrtf((float)(cnt[i] + 1));
}

__global__ __launch_bounds__(256) void scan_partial(const int* cnt, int* partial, int n) {
    __shared__ int sd[256];
    int base = blockIdx.x * SCAN_CHUNK;
    int s = 0;
    for (int j = threadIdx.x; j < SCAN_CHUNK; j += 256) {
        int i = base + j;
        if (i < n) s += cnt[i];
    }
    sd[threadIdx.x] = s;
    __syncthreads();
    for (int off = 128; off > 0; off >>= 1) {
        if (threadIdx.x < off) sd[threadIdx.x] += sd[threadIdx.x + off];
        __syncthreads();
    }
    if (threadIdx.x == 0) partial[blockIdx.x] = sd[0];
}

__global__ void scan_serial(int* partial, int* offs, int nblk, int n) {
    if (threadIdx.x == 0 && blockIdx.x == 0) {
        int run = 0;
        for (int b = 0; b < nblk; ++b) { int t = partial[b]; partial[b] = run; run += t; }
        offs[n] = run;
    }
}

__global__ __launch_bounds__(256) void scan_final(const int* cnt, const int* partial,
                                                  int* offs, int n) {
    __shared__ int sd[256];
    int base = blockIdx.x * SCAN_CHUNK;
    int t = threadIdx.x;
    int loc[4]; int ts = 0;
#pragma unroll
    for (int j = 0; j < 4; ++j) {
        int i = base + t * 4 + j;
        loc[j] = (i < n) ? cnt[i] : 0;
        ts += loc[j];
    }
    sd[t] = ts;
    __syncthreads();
    for (int off = 1; off < 256; off <<= 1) {
        int v = (t >= off) ? sd[t - off] : 0;
        __syncthreads();
        sd[t] += v;
        __syncthreads();
    }
    int excl = sd[t] - ts + partial[blockIdx.x];
#pragma unroll
    for (int j = 0; j < 4; ++j) {
        int i = base + t * 4 + j;
        if (i < n) offs[i] = excl;
        excl += loc[j];
    }
}

__global__ __launch_bounds__(256) void copy_int(const int* src, int* dst, int n) {
    int i = blockIdx.x * 256 + threadIdx.x;
    if (i < n) dst[i] = src[i];
}

__global__ __launch_bounds__(256) void fill_csr_win(const void* ei, int* cursor, int* csr,
                                                    long long E, const int* flag,
                                                    int npw, int n) {
    int w = blockIdx.x & (NXCD - 1);
    int b = blockIdx.x >> 3;
    int lo = w * npw;
    int hi = lo + npw; if (hi > n) hi = n;
    long long e0 = ((long long)b * 256 + threadIdx.x) * EPT;
    if (e0 >= E) return;
    int is64 = *flag;
    if (e0 + EPT <= E && (E & 7) == 0) {
        int c[EPT];
        load_idx8_nt(ei, E + e0, is64, c);
#pragma unroll
        for (int j = 0; j < EPT; ++j) {
            if (c[j] >= lo && c[j] < hi) {
                int row = load_idx(ei, e0 + j, is64);
                int pos = atomicAdd(&cursor[c[j]], 1);
                csr[pos] = row;
            }
        }
    } else {
        for (long long e = e0; e < E && e < e0 + EPT; ++e) {
            int col = load_idx(ei, E + e, is64);
            if (col >= lo && col < hi) {
                int row = load_idx(ei, e, is64);
                int pos = atomicAdd(&cursor[col], 1);
                csr[pos] = row;
            }
        }
    }
}

// ---------------------------------------------------------------------------
// tier 3: scatter fallback (m pre-scaled)
// ---------------------------------------------------------------------------
__global__ __launch_bounds__(256) void scatter1(const float* __restrict__ m1s,
                                                const void* ei,
                                                float* __restrict__ h,
                                                long long E, const int* flag) {
    long long e = (long long)blockIdx.x * 8 + (threadIdx.x >> 5);
    int c = threadIdx.x & 31;
    if (e >= E) return;
    int is64 = *flag;
    int row = load_idx(ei, e, is64);
    int col = load_idx(ei, E + e, is64);
    atomicAdd(&h[(long long)col * HID + c], m1s[(long long)row * HID + c]);
}

__global__ __launch_bounds__(256) void fixup1(const float* __restrict__ m1s,
                                              const float* __restrict__ dinv,
                                              const float* __restrict__ b1,
                                              float* __restrict__ h, int n) {
    long long t = (long long)blockIdx.x * 256 + threadIdx.x;
    long long node = t >> 5; int c = (int)(t & 31);
    if (node >= n) return;
    float v = (h[node * HID + c] + m1s[node * HID + c]) * dinv[node] + b1[c];
    h[node * HID + c] = v > 0.f ? v : 0.f;
}

__global__ __launch_bounds__(256) void scatter2(const float* __restrict__ m2s,
                                                const void* ei,
                                                float* __restrict__ out,
                                                long long E, const int* flag) {
    long long e = (long long)blockIdx.x * 16 + (threadIdx.x >> 4);
    int c = threadIdx.x & 15;
    if (e >= E) return;
    int is64 = *flag;
    int row = load_idx(ei, e, is64);
    int col = load_idx(ei, E + e, is64);
    atomicAdd(&out[(long long)col * OUT_CH + c], m2s[(long long)row * OUT_CH + c]);
}

__global__ __launch_bounds__(256) void fixup2(const float* __restrict__ m2s,
                                              const float* __restrict__ dinv,
                                              const float* __restrict__ b2,
                                              float* __restrict__ out, int n) {
    long long t = (long long)blockIdx.x * 256 + threadIdx.x;
    long long node = t >> 4; int c = (int)(t & 15);
    if (node >= n) return;
    out[node * OUT_CH + c] = (out[node * OUT_CH + c] + m2s[node * OUT_CH + c]) * dinv[node] + b2[c];
}

// ---------------------------------------------------------------------------
extern "C" void kernel_launch(void* const* d_in, const int* in_sizes, int n_in,
                              void* d_out, int out_size, void* d_ws, size_t ws_size,
                              hipStream_t stream) {
    const float* x  = (const float*)d_in[0];
    const void*  ei = d_in[1];
    const float* W1 = (const float*)d_in[2];
    const float* b1 = (const float*)d_in[3];
    const float* W2 = (const float*)d_in[4];
    const float* b2 = (const float*)d_in[5];
    float* out = (float*)d_out;

    const int n = in_sizes[0] / IN_CH;           // 100000
    const long long E = in_sizes[1] / 2;         // 6400000
    const int nb = (n + NPW - 1) / NPW;          // 782

    char* w = (char*)d_ws;
    size_t used = 0;
    auto carve = [&](size_t bytes) -> void* {
        void* p = (void*)(w + used);
        used += (bytes + 255) & ~(size_t)255;
        return p;
    };
    auto A = [](size_t b) -> size_t { return (b + 255) & ~(size_t)255; };

    int*   bstart  = (int*)carve((size_t)(NB_MAX + 1) * 4);
    int*   btot    = (int*)carve((size_t)NB_MAX * 4);
    float* dinv    = (float*)carve((size_t)n * 4);
    int*   flag    = (int*)carve(256);
    int*   offs    = (int*)carve((size_t)(n + 1) * 4);
    int*   cnt     = (int*)carve((size_t)n * 4);
    int*   partial = (int*)carve(4096);
    const size_t base = used;

    const size_t bhistB = A((size_t)nb * FB_GRID * 4);
    const size_t needT1 = base + bhistB + 2 * A((size_t)E * 4) + 2 * A((size_t)n * HID * 4);
    const size_t needT2 = base + A((size_t)E * 4) + 2 * A((size_t)n * HID * 4);
    const size_t needT3 = base + 2 * A((size_t)n * HID * 4);
    const bool tier1 = (ws_size >= needT1) && (n <= 131071) && (nb <= NB_MAX);
    const bool tier2 = !tier1 && (ws_size >= needT2) && (n <= 131071);

    const int nblkN  = (n + 255) / 256;
    const int nblkEv = (int)((E + 256LL * EPT - 1) / (256LL * EPT));
    const int nblkSc = (n + SCAN_CHUNK - 1) / SCAN_CHUNK;
    const int nblkH  = (int)(((long long)n * HID + 255) / 256);
    const int nblkO  = (int)(((long long)n * OUT_CH + 255) / 256);

    detect_dtype<<<1, 64, 0, stream>>>(ei, E, n, flag);

    if (tier1) {
        int*   bhist    = (int*)carve((size_t)nb * FB_GRID * 4);
        int*   bucketed = (int*)carve((size_t)E * 4);
        int*   csr      = (int*)carve((size_t)E * 4);
        float* m1 = (float*)carve((size_t)n * HID * 4);
        float* h  = (float*)carve((size_t)n * HID * 4);
        float* m2 = m1;                            // m1 dead after agg1

        const long long chunk = (((E + FB_GRID - 1) / FB_GRID) + 7) & ~7LL;

        bucket_hist<<<FB_GRID, FB_THREADS, 0, stream>>>(ei, E, flag, bhist, nb, chunk);
        scan_blocks<<<nb, FB_GRID, 0, stream>>>(bhist, btot, nb);
        scan_buckets<<<1, 1024, 0, stream>>>(btot, bstart, nb);
        fill_bucket<<<FB_GRID, FB_THREADS, 0, stream>>>(ei, E, flag, bhist, bstart,
                                                        bucketed, nb, chunk);
        csr_sort<<<nb, 512, 0, stream>>>(bucketed, bstart, csr, offs, dinv, nb, n);

        gemm1p<<<(n + 7) / 8, 256, 0, stream>>>(x, W1, dinv, m1, n);
        agg1<<<(n + 7) / 8, 256, 0, stream>>>(m1, csr, offs, dinv, b1, h, n);
        gemm2p<<<nblkO, 256, 0, stream>>>(h, W2, dinv, m2, n);
        agg2<<<(n + 15) / 16, 256, 0, stream>>>(m2, csr, offs, dinv, b2, out, n);
    } else if (tier2) {
        int*   csr = (int*)carve((size_t)E * 4);
        float* m1  = (float*)carve((size_t)n * HID * 4);
        float* h   = (float*)carve((size_t)n * HID * 4);
        float* m2  = m1;

        zero_int<<<nblkN, 256, 0, stream>>>(cnt, n);
        count_edges<<<nblkEv, 256, 0, stream>>>(ei, cnt, E, flag);
        compute_dinv<<<nblkN, 256, 0, stream>>>(cnt, dinv, n);
        scan_partial<<<nblkSc, 256, 0, stream>>>(cnt, partial, n);
        scan_serial<<<1, 64, 0, stream>>>(partial, offs, nblkSc, n);
        scan_final<<<nblkSc, 256, 0, stream>>>(cnt, partial, offs, n);
        copy_int<<<nblkN, 256, 0, stream>>>(offs, cnt, n);

        const int npw2 = (n + NXCD - 1) / NXCD;
        fill_csr_win<<<nblkEv * NXCD, 256, 0, stream>>>(ei, cnt, csr, E, flag, npw2, n);

        gemm1p<<<(n + 7) / 8, 256, 0, stream>>>(x, W1, dinv, m1, n);
        agg1<<<(n + 7) / 8, 256, 0, stream>>>(m1, csr, offs, dinv, b1, h, n);
        gemm2p<<<nblkO, 256, 0, stream>>>(h, W2, dinv, m2, n);
        agg2<<<(n + 15) / 16, 256, 0, stream>>>(m2, csr, offs, dinv, b2, out, n);
    } else if (ws_size >= needT3) {
        float* m1 = (float*)carve((size_t)n * HID * 4);
        float* h  = (float*)carve((size_t)n * HID * 4);
        float* m2 = m1;

        zero_int<<<nblkN, 256, 0, stream>>>(cnt, n);
        count_edges<<<nblkEv, 256, 0, stream>>>(ei, cnt, E, flag);
        compute_dinv<<<nblkN, 256, 0, stream>>>(cnt, dinv, n);

        gemm1p<<<(n + 7) / 8, 256, 0, stream>>>(x, W1, dinv, m1, n);
        zero_float<<<nblkH, 256, 0, stream>>>(h, (long long)n * HID);
        scatter1<<<(int)((E + 7) / 8), 256, 0, stream>>>(m1, ei, h, E, flag);
        fixup1<<<nblkH, 256, 0, stream>>>(m1, dinv, b1, h, n);
        gemm2p<<<nblkO, 256, 0, stream>>>(h, W2, dinv, m2, n);
        zero_float<<<nblkO, 256, 0, stream>>>(out, (long long)n * OUT_CH);
        scatter2<<<(int)((E + 15) / 16), 256, 0, stream>>>(m2, ei, out, E, flag);
        fixup2<<<nblkO, 256, 0, stream>>>(m2, dinv, b2, out, n);
    }
}

// Round 10
// 305.423 us; speedup vs baseline: 7.2452x; 1.1724x over previous
//
#include <hip/hip_runtime.h>
#include <hip/hip_bf16.h>

#define IN_CH 128
#define HID 32
#define OUT_CH 16
#define NPW 128           // nodes per bucket (col >> 7)
#define NPW_SHIFT 7
#define NB_MAX 1024
#define FB_GRID 256       // blocks in hist/fill
#define FB_THREADS 1024
#define CAP 12288         // LDS edge capacity in csr_sort (48 KB)
#define SCAN_CHUNK 1024
#define NXCD 8
#define EPT 8

typedef int vint4 __attribute__((ext_vector_type(4)));
typedef vint4 vint4u __attribute__((aligned(4)));   // 4B-aligned vector load

// ---------------------------------------------------------------------------
// dtype sniff: 64 parallel probe loads + ballot (was a 20us serial loop)
// ---------------------------------------------------------------------------
__global__ void detect_dtype(const void* ei, long long ecount, int n, int* flag) {
    int lane = threadIdx.x;
    const long long* p = (const long long*)ei;
    long long st = ecount / 64; if (st < 1) st = 1;
    long long idx = (long long)lane * st;
    bool ok = true;
    if (idx < ecount) {
        long long v = p[idx];
        ok = (v >= 0 && v < n);
    }
    unsigned long long mask = __ballot(ok);
    if (lane == 0) *flag = (mask == ~0ULL) ? 1 : 0;
}

__device__ __forceinline__ int load_idx(const void* ei, long long i, int is64) {
    return is64 ? (int)((const long long*)ei)[i] : ((const int*)ei)[i];
}

// 8 consecutive indices, nontemporal; offset must be 8-element aligned
__device__ __forceinline__ void load_idx8_nt(const void* ei, long long off, int is64,
                                             int* c) {
    if (is64) {
        const long long* p = (const long long*)ei + off;
#pragma unroll
        for (int j = 0; j < 8; ++j) c[j] = (int)__builtin_nontemporal_load(p + j);
    } else {
        vint4 v0 = __builtin_nontemporal_load((const vint4*)((const int*)ei + off));
        vint4 v1 = __builtin_nontemporal_load((const vint4*)((const int*)ei + off + 4));
        c[0] = v0.x; c[1] = v0.y; c[2] = v0.z; c[3] = v0.w;
        c[4] = v1.x; c[5] = v1.y; c[6] = v1.z; c[7] = v1.w;
    }
}

__device__ __forceinline__ float bf_lo(unsigned int u) { return __uint_as_float(u << 16); }
__device__ __forceinline__ float bf_hi(unsigned int u) { return __uint_as_float(u & 0xFFFF0000u); }

// ---------------------------------------------------------------------------
__global__ __launch_bounds__(256) void zero_int(int* p, int n) {
    int i = blockIdx.x * 256 + threadIdx.x;
    if (i < n) p[i] = 0;
}

__global__ __launch_bounds__(256) void zero_float(float* p, long long n) {
    long long i = (long long)blockIdx.x * 256 + threadIdx.x;
    if (i < n) p[i] = 0.f;
}

// ---------------------------------------------------------------------------
// pass A: per-block LDS histogram -> bhist[bucket*FB_GRID+blk]
// ---------------------------------------------------------------------------
__global__ __launch_bounds__(FB_THREADS) void bucket_hist(const void* ei, long long E,
                                                          const int* flag, int* bhist,
                                                          int nb, long long chunk) {
    __shared__ int hist[NB_MAX];
    for (int i = threadIdx.x; i < nb; i += FB_THREADS) hist[i] = 0;
    __syncthreads();
    long long lo = (long long)blockIdx.x * chunk;
    long long hi = lo + chunk; if (hi > E) hi = E;
    int is64 = *flag;
    if ((E & 7) == 0) {
        for (long long e = lo + (long long)threadIdx.x * EPT; e + EPT <= hi;
             e += (long long)FB_THREADS * EPT) {
            int c[8]; load_idx8_nt(ei, E + e, is64, c);
#pragma unroll
            for (int j = 0; j < 8; ++j) atomicAdd(&hist[c[j] >> NPW_SHIFT], 1);
        }
    } else {
        for (long long e = lo + threadIdx.x; e < hi; e += FB_THREADS)
            atomicAdd(&hist[load_idx(ei, E + e, is64) >> NPW_SHIFT], 1);
    }
    __syncthreads();
    for (int b = threadIdx.x; b < nb; b += FB_THREADS)
        bhist[b * FB_GRID + blockIdx.x] = hist[b];
}

// pass B: per-bucket exclusive scan over FB_GRID block counts + totals
__global__ __launch_bounds__(256) void scan_blocks(int* bhist, int* btot, int nb) {
    __shared__ int sd[FB_GRID];
    int b = blockIdx.x, t = threadIdx.x;
    int* p = bhist + (long long)b * FB_GRID;
    int v = p[t];
    sd[t] = v; __syncthreads();
    for (int off = 1; off < FB_GRID; off <<= 1) {
        int u = (t >= off) ? sd[t - off] : 0;
        __syncthreads(); sd[t] += u; __syncthreads();
    }
    p[t] = sd[t] - v;
    if (t == FB_GRID - 1) btot[b] = sd[t];
}

// pass C: exclusive scan over nb bucket totals, one block
__global__ __launch_bounds__(1024) void scan_buckets(const int* btot, int* bstart, int nb) {
    __shared__ int sd[1024];
    int t = threadIdx.x;
    int a0 = (2 * t < nb) ? btot[2 * t] : 0;
    int a1 = (2 * t + 1 < nb) ? btot[2 * t + 1] : 0;
    sd[t] = a0 + a1; __syncthreads();
    for (int off = 1; off < 1024; off <<= 1) {
        int v = (t >= off) ? sd[t - off] : 0;
        __syncthreads(); sd[t] += v; __syncthreads();
    }
    int excl = sd[t] - (a0 + a1);
    if (2 * t < nb)     bstart[2 * t] = excl;
    if (2 * t + 1 < nb) bstart[2 * t + 1] = excl + a0;
    if (t == 1023) bstart[nb] = sd[t];
}

// ---------------------------------------------------------------------------
// pass D: single-pass dense-write fill (LDS cursors, disjoint ranges)
// ---------------------------------------------------------------------------
__global__ __launch_bounds__(FB_THREADS) void fill_bucket(const void* ei, long long E,
                                                          const int* flag,
                                                          const int* bhist,
                                                          const int* bstart,
                                                          int* bucketed, int nb,
                                                          long long chunk) {
    __shared__ int cur[NB_MAX];
    for (int b = threadIdx.x; b < nb; b += FB_THREADS)
        cur[b] = bstart[b] + bhist[b * FB_GRID + blockIdx.x];
    __syncthreads();
    long long lo = (long long)blockIdx.x * chunk;
    long long hi = lo + chunk; if (hi > E) hi = E;
    int is64 = *flag;
    if ((E & 7) == 0) {
        for (long long e = lo + (long long)threadIdx.x * EPT; e + EPT <= hi;
             e += (long long)FB_THREADS * EPT) {
            int c[8], r[8];
            load_idx8_nt(ei, E + e, is64, c);
            load_idx8_nt(ei, e, is64, r);
#pragma unroll
            for (int j = 0; j < 8; ++j) {
                int b = c[j] >> NPW_SHIFT;
                int pos = atomicAdd(&cur[b], 1);
                bucketed[pos] = r[j] | ((c[j] & (NPW - 1)) << 17);
            }
        }
    } else {
        for (long long e = lo + threadIdx.x; e < hi; e += FB_THREADS) {
            int col = load_idx(ei, E + e, is64);
            int row = load_idx(ei, e, is64);
            int b = col >> NPW_SHIFT;
            int pos = atomicAdd(&cur[b], 1);
            bucketed[pos] = row | ((col & (NPW - 1)) << 17);
        }
    }
}

// ---------------------------------------------------------------------------
// per-bucket node sort: LDS-stage, NPW-node hist, emit offs/dinv + csr
// ---------------------------------------------------------------------------
__global__ __launch_bounds__(512) void csr_sort(const int* __restrict__ bucketed,
                                                const int* __restrict__ bstart,
                                                int* __restrict__ csr,
                                                int* __restrict__ offs,
                                                float* __restrict__ dinv,
                                                int nb, int n) {
    __shared__ int lds_e[CAP];
    __shared__ int hist[NPW];
    __shared__ int cur[NPW];
    int b = blockIdx.x, t = threadIdx.x;
    int s0 = bstart[b], s1 = bstart[b + 1];
    int cnt = s1 - s0;
    if (t < NPW) hist[t] = 0;
    __syncthreads();
    bool fit = (cnt <= CAP);
    int cnt4 = cnt & ~3;
    if (fit) {
        for (int i = t * 4; i < cnt4; i += 2048) {
            vint4u e4 = *(const vint4u*)(bucketed + s0 + i);
            lds_e[i + 0] = e4.x; atomicAdd(&hist[e4.x >> 17], 1);
            lds_e[i + 1] = e4.y; atomicAdd(&hist[e4.y >> 17], 1);
            lds_e[i + 2] = e4.z; atomicAdd(&hist[e4.z >> 17], 1);
            lds_e[i + 3] = e4.w; atomicAdd(&hist[e4.w >> 17], 1);
        }
        for (int i = cnt4 + t; i < cnt; i += 512) {
            int e = bucketed[s0 + i];
            lds_e[i] = e;
            atomicAdd(&hist[e >> 17], 1);
        }
    } else {
        for (int i = t * 4; i < cnt4; i += 2048) {
            vint4u e4 = *(const vint4u*)(bucketed + s0 + i);
            atomicAdd(&hist[e4.x >> 17], 1);
            atomicAdd(&hist[e4.y >> 17], 1);
            atomicAdd(&hist[e4.z >> 17], 1);
            atomicAdd(&hist[e4.w >> 17], 1);
        }
        for (int i = cnt4 + t; i < cnt; i += 512)
            atomicAdd(&hist[bucketed[s0 + i] >> 17], 1);
    }
    __syncthreads();
    if (t == 0) {
        int run = 0;
        for (int k = 0; k < NPW; ++k) { cur[k] = run; run += hist[k]; }
    }
    __syncthreads();
    if (t < NPW) {
        int node = b * NPW + t;
        if (node < n) {
            offs[node] = s0 + cur[t];
            dinv[node] = 1.0f / sqrtf((float)(hist[t] + 1));  // +1 self loop
        }
    }
    if (b == nb - 1 && t == 0) offs[n] = s1;
    __syncthreads();
    if (fit) {
        for (int i = t; i < cnt; i += 512) {
            int e = lds_e[i];
            int pos = atomicAdd(&cur[e >> 17], 1);
            csr[s0 + pos] = e & 0x1FFFF;
        }
    } else {
        for (int i = t; i < cnt; i += 512) {
            int e = bucketed[s0 + i];
            int pos = atomicAdd(&cur[e >> 17], 1);
            csr[s0 + pos] = e & 0x1FFFF;
        }
    }
}

// ---------------------------------------------------------------------------
// GEMMs, dinv pre-multiplied; BF16=1 writes bf16 (halves agg gather bytes)
// ---------------------------------------------------------------------------
template <int BF16>
__global__ __launch_bounds__(256) void gemm1p(const float* __restrict__ x,
                                              const float* __restrict__ W1,
                                              const float* __restrict__ dinv,
                                              float* __restrict__ m1f,
                                              __hip_bfloat16* __restrict__ m1b, int n) {
    __shared__ float sW[IN_CH * HID];
    __shared__ float sx[8][IN_CH];
    for (int i = threadIdx.x; i < IN_CH * HID; i += 256) sW[i] = W1[i];
    int g = threadIdx.x >> 5;
    int c = threadIdx.x & 31;
    long long node = (long long)blockIdx.x * 8 + g;
    bool active = node < n;
    if (active) {
        const float4* xr = (const float4*)(x + node * IN_CH);
        float4 v = xr[c];
        sx[g][c * 4 + 0] = v.x; sx[g][c * 4 + 1] = v.y;
        sx[g][c * 4 + 2] = v.z; sx[g][c * 4 + 3] = v.w;
    }
    __syncthreads();
    if (!active) return;
    float acc = 0.f;
#pragma unroll
    for (int k = 0; k < IN_CH; ++k)
        acc = fmaf(sx[g][k], sW[k * HID + c], acc);
    float v = acc * dinv[node];
    if (BF16) m1b[(node << 5) + c] = __float2bfloat16(v);
    else      m1f[(node << 5) + c] = v;
}

template <int BF16>
__global__ __launch_bounds__(256) void gemm2p(const float* __restrict__ h,
                                              const float* __restrict__ W2,
                                              const float* __restrict__ dinv,
                                              float* __restrict__ m2f,
                                              __hip_bfloat16* __restrict__ m2b, int n) {
    __shared__ float sW[HID * OUT_CH];
    for (int i = threadIdx.x; i < HID * OUT_CH; i += 256) sW[i] = W2[i];
    __syncthreads();
    long long t = (long long)blockIdx.x * 256 + threadIdx.x;
    long long node = t >> 4;
    int c = (int)(t & 15);
    if (node >= n) return;
    const float* hr = h + node * HID;
    float acc = 0.f;
#pragma unroll
    for (int k = 0; k < HID; ++k)
        acc = fmaf(hr[k], sW[k * OUT_CH + c], acc);
    float v = acc * dinv[node];
    if (BF16) m2b[(node << 4) + c] = __float2bfloat16(v);
    else      m2f[(node << 4) + c] = v;
}

// ---------------------------------------------------------------------------
// bf16 CSR gather aggregation: 16 lanes/node, bf16x2 per lane (64B/row = 1 line)
// ---------------------------------------------------------------------------
__global__ __launch_bounds__(256) void agg1_bf(const unsigned int* __restrict__ m1b,
                                               const int* __restrict__ csr,
                                               const int* __restrict__ offs,
                                               const float* __restrict__ dinv,
                                               const float* __restrict__ b1,
                                               float* __restrict__ h, int n) {
    int g = threadIdx.x >> 4;
    int c = threadIdx.x & 15;
    long long node = (long long)blockIdx.x * 16 + g;
    if (node >= n) return;
    unsigned int us = m1b[(node << 4) + c];          // self loop
    float accL = bf_lo(us), accH = bf_hi(us);
    int s = offs[node], e1 = offs[node + 1];
    for (; s + 7 < e1; s += 8) {
        vint4u a = *(const vint4u*)(csr + s);
        vint4u b = *(const vint4u*)(csr + s + 4);
        unsigned int u0 = m1b[((long long)a.x << 4) + c];
        unsigned int u1 = m1b[((long long)a.y << 4) + c];
        unsigned int u2 = m1b[((long long)a.z << 4) + c];
        unsigned int u3 = m1b[((long long)a.w << 4) + c];
        unsigned int u4 = m1b[((long long)b.x << 4) + c];
        unsigned int u5 = m1b[((long long)b.y << 4) + c];
        unsigned int u6 = m1b[((long long)b.z << 4) + c];
        unsigned int u7 = m1b[((long long)b.w << 4) + c];
        accL += bf_lo(u0); accH += bf_hi(u0);
        accL += bf_lo(u1); accH += bf_hi(u1);
        accL += bf_lo(u2); accH += bf_hi(u2);
        accL += bf_lo(u3); accH += bf_hi(u3);
        accL += bf_lo(u4); accH += bf_hi(u4);
        accL += bf_lo(u5); accH += bf_hi(u5);
        accL += bf_lo(u6); accH += bf_hi(u6);
        accL += bf_lo(u7); accH += bf_hi(u7);
    }
    for (; s < e1; ++s) {
        unsigned int u = m1b[((long long)csr[s] << 4) + c];
        accL += bf_lo(u); accH += bf_hi(u);
    }
    float di = dinv[node];
    float vL = accL * di + b1[2 * c];
    float vH = accH * di + b1[2 * c + 1];
    float2 val;
    val.x = vL > 0.f ? vL : 0.f;
    val.y = vH > 0.f ? vH : 0.f;
    *(float2*)(h + (node << 5) + 2 * c) = val;
}

// 8 lanes/node, bf16x2 per lane (32B/row)
__global__ __launch_bounds__(256) void agg2_bf(const unsigned int* __restrict__ m2b,
                                               const int* __restrict__ csr,
                                               const int* __restrict__ offs,
                                               const float* __restrict__ dinv,
                                               const float* __restrict__ b2,
                                               float* __restrict__ out, int n) {
    int g = threadIdx.x >> 3;
    int c = threadIdx.x & 7;
    long long node = (long long)blockIdx.x * 32 + g;
    if (node >= n) return;
    unsigned int us = m2b[(node << 3) + c];
    float accL = bf_lo(us), accH = bf_hi(us);
    int s = offs[node], e1 = offs[node + 1];
    for (; s + 7 < e1; s += 8) {
        vint4u a = *(const vint4u*)(csr + s);
        vint4u b = *(const vint4u*)(csr + s + 4);
        unsigned int u0 = m2b[((long long)a.x << 3) + c];
        unsigned int u1 = m2b[((long long)a.y << 3) + c];
        unsigned int u2 = m2b[((long long)a.z << 3) + c];
        unsigned int u3 = m2b[((long long)a.w << 3) + c];
        unsigned int u4 = m2b[((long long)b.x << 3) + c];
        unsigned int u5 = m2b[((long long)b.y << 3) + c];
        unsigned int u6 = m2b[((long long)b.z << 3) + c];
        unsigned int u7 = m2b[((long long)b.w << 3) + c];
        accL += bf_lo(u0); accH += bf_hi(u0);
        accL += bf_lo(u1); accH += bf_hi(u1);
        accL += bf_lo(u2); accH += bf_hi(u2);
        accL += bf_lo(u3); accH += bf_hi(u3);
        accL += bf_lo(u4); accH += bf_hi(u4);
        accL += bf_lo(u5); accH += bf_hi(u5);
        accL += bf_lo(u6); accH += bf_hi(u6);
        accL += bf_lo(u7); accH += bf_hi(u7);
    }
    for (; s < e1; ++s) {
        unsigned int u = m2b[((long long)csr[s] << 3) + c];
        accL += bf_lo(u); accH += bf_hi(u);
    }
    float di = dinv[node];
    float2 val;
    val.x = accL * di + b2[2 * c];
    val.y = accH * di + b2[2 * c + 1];
    *(float2*)(out + (node << 4) + 2 * c) = val;
}

// ---------------------------------------------------------------------------
// tier 2: windowed CSR fill path
// ---------------------------------------------------------------------------
__global__ __launch_bounds__(256) void count_edges(const void* ei, int* cnt,
                                                   long long E, const int* flag) {
    long long e0 = ((long long)blockIdx.x * 256 + threadIdx.x) * EPT;
    if (e0 >= E) return;
    int is64 = *flag;
    if (e0 + EPT <= E && (E & 7) == 0) {
        int c[EPT];
        load_idx8_nt(ei, E + e0, is64, c);
#pragma unroll
        for (int j = 0; j < EPT; ++j) atomicAdd(&cnt[c[j]], 1);
    } else {
        for (long long e = e0; e < E && e < e0 + EPT; ++e)
            atomicAdd(&cnt[load_idx(ei, E + e, is64)], 1);
    }
}

__global__ __launch_bounds__(256) void compute_dinv(const int* cnt, float* dinv, int n) {
    int i = blockIdx.x * 256 + threadIdx.x;
    if (i < n) dinv[i] = 1.0f / sqrtf((float)(cnt[i] + 1));
}

__global__ __launch_bounds__(256) void scan_partial(const int* cnt, int* partial, int n) {
    __shared__ int sd[256];
    int base = blockIdx.x * SCAN_CHUNK;
    int s = 0;
    for (int j = threadIdx.x; j < SCAN_CHUNK; j += 256) {
        int i = base + j;
        if (i < n) s += cnt[i];
    }
    sd[threadIdx.x] = s;
    __syncthreads();
    for (int off = 128; off > 0; off >>= 1) {
        if (threadIdx.x < off) sd[threadIdx.x] += sd[threadIdx.x + off];
        __syncthreads();
    }
    if (threadIdx.x == 0) partial[blockIdx.x] = sd[0];
}

__global__ void scan_serial(int* partial, int* offs, int nblk, int n) {
    if (threadIdx.x == 0 && blockIdx.x == 0) {
        int run = 0;
        for (int b = 0; b < nblk; ++b) { int t = partial[b]; partial[b] = run; run += t; }
        offs[n] = run;
    }
}

__global__ __launch_bounds__(256) void scan_final(const int* cnt, const int* partial,
                                                  int* offs, int n) {
    __shared__ int sd[256];
    int base = blockIdx.x * SCAN_CHUNK;
    int t = threadIdx.x;
    int loc[4]; int ts = 0;
#pragma unroll
    for (int j = 0; j < 4; ++j) {
        int i = base + t * 4 + j;
        loc[j] = (i < n) ? cnt[i] : 0;
        ts += loc[j];
    }
    sd[t] = ts;
    __syncthreads();
    for (int off = 1; off < 256; off <<= 1) {
        int v = (t >= off) ? sd[t - off] : 0;
        __syncthreads();
        sd[t] += v;
        __syncthreads();
    }
    int excl = sd[t] - ts + partial[blockIdx.x];
#pragma unroll
    for (int j = 0; j < 4; ++j) {
        int i = base + t * 4 + j;
        if (i < n) offs[i] = excl;
        excl += loc[j];
    }
}

__global__ __launch_bounds__(256) void copy_int(const int* src, int* dst, int n) {
    int i = blockIdx.x * 256 + threadIdx.x;
    if (i < n) dst[i] = src[i];
}

__global__ __launch_bounds__(256) void fill_csr_win(const void* ei, int* cursor, int* csr,
                                                    long long E, const int* flag,
                                                    int npw, int n) {
    int w = blockIdx.x & (NXCD - 1);
    int b = blockIdx.x >> 3;
    int lo = w * npw;
    int hi = lo + npw; if (hi > n) hi = n;
    long long e0 = ((long long)b * 256 + threadIdx.x) * EPT;
    if (e0 >= E) return;
    int is64 = *flag;
    if (e0 + EPT <= E && (E & 7) == 0) {
        int c[EPT];
        load_idx8_nt(ei, E + e0, is64, c);
#pragma unroll
        for (int j = 0; j < EPT; ++j) {
            if (c[j] >= lo && c[j] < hi) {
                int row = load_idx(ei, e0 + j, is64);
                int pos = atomicAdd(&cursor[c[j]], 1);
                csr[pos] = row;
            }
        }
    } else {
        for (long long e = e0; e < E && e < e0 + EPT; ++e) {
            int col = load_idx(ei, E + e, is64);
            if (col >= lo && col < hi) {
                int row = load_idx(ei, e, is64);
                int pos = atomicAdd(&cursor[col], 1);
                csr[pos] = row;
            }
        }
    }
}

// ---------------------------------------------------------------------------
// tier 3: scatter fallback (fp32, m pre-scaled)
// ---------------------------------------------------------------------------
__global__ __launch_bounds__(256) void scatter1(const float* __restrict__ m1s,
                                                const void* ei,
                                                float* __restrict__ h,
                                                long long E, const int* flag) {
    long long e = (long long)blockIdx.x * 8 + (threadIdx.x >> 5);
    int c = threadIdx.x & 31;
    if (e >= E) return;
    int is64 = *flag;
    int row = load_idx(ei, e, is64);
    int col = load_idx(ei, E + e, is64);
    atomicAdd(&h[(long long)col * HID + c], m1s[(long long)row * HID + c]);
}

__global__ __launch_bounds__(256) void fixup1(const float* __restrict__ m1s,
                                              const float* __restrict__ dinv,
                                              const float* __restrict__ b1,
                                              float* __restrict__ h, int n) {
    long long t = (long long)blockIdx.x * 256 + threadIdx.x;
    long long node = t >> 5; int c = (int)(t & 31);
    if (node >= n) return;
    float v = (h[node * HID + c] + m1s[node * HID + c]) * dinv[node] + b1[c];
    h[node * HID + c] = v > 0.f ? v : 0.f;
}

__global__ __launch_bounds__(256) void scatter2(const float* __restrict__ m2s,
                                                const void* ei,
                                                float* __restrict__ out,
                                                long long E, const int* flag) {
    long long e = (long long)blockIdx.x * 16 + (threadIdx.x >> 4);
    int c = threadIdx.x & 15;
    if (e >= E) return;
    int is64 = *flag;
    int row = load_idx(ei, e, is64);
    int col = load_idx(ei, E + e, is64);
    atomicAdd(&out[(long long)col * OUT_CH + c], m2s[(long long)row * OUT_CH + c]);
}

__global__ __launch_bounds__(256) void fixup2(const float* __restrict__ m2s,
                                              const float* __restrict__ dinv,
                                              const float* __restrict__ b2,
                                              float* __restrict__ out, int n) {
    long long t = (long long)blockIdx.x * 256 + threadIdx.x;
    long long node = t >> 4; int c = (int)(t & 15);
    if (node >= n) return;
    out[node * OUT_CH + c] = (out[node * OUT_CH + c] + m2s[node * OUT_CH + c]) * dinv[node] + b2[c];
}

// ---------------------------------------------------------------------------
extern "C" void kernel_launch(void* const* d_in, const int* in_sizes, int n_in,
                              void* d_out, int out_size, void* d_ws, size_t ws_size,
                              hipStream_t stream) {
    const float* x  = (const float*)d_in[0];
    const void*  ei = d_in[1];
    const float* W1 = (const float*)d_in[2];
    const float* b1 = (const float*)d_in[3];
    const float* W2 = (const float*)d_in[4];
    const float* b2 = (const float*)d_in[5];
    float* out = (float*)d_out;

    const int n = in_sizes[0] / IN_CH;           // 100000
    const long long E = in_sizes[1] / 2;         // 6400000
    const int nb = (n + NPW - 1) / NPW;          // 782

    char* w = (char*)d_ws;
    size_t used = 0;
    auto carve = [&](size_t bytes) -> void* {
        void* p = (void*)(w + used);
        used += (bytes + 255) & ~(size_t)255;
        return p;
    };
    auto A = [](size_t b) -> size_t { return (b + 255) & ~(size_t)255; };

    int*   bstart  = (int*)carve((size_t)(NB_MAX + 1) * 4);
    int*   btot    = (int*)carve((size_t)NB_MAX * 4);
    float* dinv    = (float*)carve((size_t)n * 4);
    int*   flag    = (int*)carve(256);
    int*   offs    = (int*)carve((size_t)(n + 1) * 4);
    int*   cnt     = (int*)carve((size_t)n * 4);
    int*   partial = (int*)carve(4096);
    const size_t base = used;

    const size_t bhistB = A((size_t)nb * FB_GRID * 4);
    const size_t mbB    = A((size_t)n * HID * 2);   // bf16 m1 (reused as m2)
    const size_t hB     = A((size_t)n * HID * 4);
    const size_t needT1 = base + bhistB + 2 * A((size_t)E * 4) + mbB + hB;
    const size_t needT2 = base + A((size_t)E * 4) + mbB + hB;
    const size_t needT3 = base + 2 * A((size_t)n * HID * 4);
    const bool tier1 = (ws_size >= needT1) && (n <= 131071) && (nb <= NB_MAX);
    const bool tier2 = !tier1 && (ws_size >= needT2) && (n <= 131071);

    const int nblkN  = (n + 255) / 256;
    const int nblkEv = (int)((E + 256LL * EPT - 1) / (256LL * EPT));
    const int nblkSc = (n + SCAN_CHUNK - 1) / SCAN_CHUNK;
    const int nblkH  = (int)(((long long)n * HID + 255) / 256);
    const int nblkO  = (int)(((long long)n * OUT_CH + 255) / 256);

    detect_dtype<<<1, 64, 0, stream>>>(ei, E, n, flag);

    if (tier1) {
        int*   bhist    = (int*)carve((size_t)nb * FB_GRID * 4);
        int*   bucketed = (int*)carve((size_t)E * 4);
        int*   csr      = (int*)carve((size_t)E * 4);
        __hip_bfloat16* m1b = (__hip_bfloat16*)carve((size_t)n * HID * 2);
        float* h  = (float*)carve((size_t)n * HID * 4);
        __hip_bfloat16* m2b = m1b;                 // m1b dead after agg1

        const long long chunk = (((E + FB_GRID - 1) / FB_GRID) + 7) & ~7LL;

        bucket_hist<<<FB_GRID, FB_THREADS, 0, stream>>>(ei, E, flag, bhist, nb, chunk);
        scan_blocks<<<nb, FB_GRID, 0, stream>>>(bhist, btot, nb);
        scan_buckets<<<1, 1024, 0, stream>>>(btot, bstart, nb);
        fill_bucket<<<FB_GRID, FB_THREADS, 0, stream>>>(ei, E, flag, bhist, bstart,
                                                        bucketed, nb, chunk);
        csr_sort<<<nb, 512, 0, stream>>>(bucketed, bstart, csr, offs, dinv, nb, n);

        gemm1p<1><<<(n + 7) / 8, 256, 0, stream>>>(x, W1, dinv, nullptr, m1b, n);
        agg1_bf<<<(n + 15) / 16, 256, 0, stream>>>((const unsigned int*)m1b, csr, offs,
                                                   dinv, b1, h, n);
        gemm2p<1><<<nblkO, 256, 0, stream>>>(h, W2, dinv, nullptr, m2b, n);
        agg2_bf<<<(n + 31) / 32, 256, 0, stream>>>((const unsigned int*)m2b, csr, offs,
                                                   dinv, b2, out, n);
    } else if (tier2) {
        int*   csr = (int*)carve((size_t)E * 4);
        __hip_bfloat16* m1b = (__hip_bfloat16*)carve((size_t)n * HID * 2);
        float* h  = (float*)carve((size_t)n * HID * 4);
        __hip_bfloat16* m2b = m1b;

        zero_int<<<nblkN, 256, 0, stream>>>(cnt, n);
        count_edges<<<nblkEv, 256, 0, stream>>>(ei, cnt, E, flag);
        compute_dinv<<<nblkN, 256, 0, stream>>>(cnt, dinv, n);
        scan_partial<<<nblkSc, 256, 0, stream>>>(cnt, partial, n);
        scan_serial<<<1, 64, 0, stream>>>(partial, offs, nblkSc, n);
        scan_final<<<nblkSc, 256, 0, stream>>>(cnt, partial, offs, n);
        copy_int<<<nblkN, 256, 0, stream>>>(offs, cnt, n);

        const int npw2 = (n + NXCD - 1) / NXCD;
        fill_csr_win<<<nblkEv * NXCD, 256, 0, stream>>>(ei, cnt, csr, E, flag, npw2, n);

        gemm1p<1><<<(n + 7) / 8, 256, 0, stream>>>(x, W1, dinv, nullptr, m1b, n);
        agg1_bf<<<(n + 15) / 16, 256, 0, stream>>>((const unsigned int*)m1b, csr, offs,
                                                   dinv, b1, h, n);
        gemm2p<1><<<nblkO, 256, 0, stream>>>(h, W2, dinv, nullptr, m2b, n);
        agg2_bf<<<(n + 31) / 32, 256, 0, stream>>>((const unsigned int*)m2b, csr, offs,
                                                   dinv, b2, out, n);
    } else if (ws_size >= needT3) {
        float* m1 = (float*)carve((size_t)n * HID * 4);
        float* h  = (float*)carve((size_t)n * HID * 4);
        float* m2 = m1;

        zero_int<<<nblkN, 256, 0, stream>>>(cnt, n);
        count_edges<<<nblkEv, 256, 0, stream>>>(ei, cnt, E, flag);
        compute_dinv<<<nblkN, 256, 0, stream>>>(cnt, dinv, n);

        gemm1p<0><<<(n + 7) / 8, 256, 0, stream>>>(x, W1, dinv, m1, nullptr, n);
        zero_float<<<nblkH, 256, 0, stream>>>(h, (long long)n * HID);
        scatter1<<<(int)((E + 7) / 8), 256, 0, stream>>>(m1, ei, h, E, flag);
        fixup1<<<nblkH, 256, 0, stream>>>(m1, dinv, b1, h, n);
        gemm2p<0><<<nblkO, 256, 0, stream>>>(h, W2, dinv, m2, nullptr, n);
        zero_float<<<nblkO, 256, 0, stream>>>(out, (long long)n * OUT_CH);
        scatter2<<<(int)((E + 15) / 16), 256, 0, stream>>>(m2, ei, out, E, flag);
        fixup2<<<nblkO, 256, 0, stream>>>(m2, dinv, b2, out, n);
    }
}

// Round 11
// 263.831 us; speedup vs baseline: 8.3873x; 1.1576x over previous
//
#include <hip/hip_runtime.h>
#include <hip/hip_bf16.h>

#define IN_CH 128
#define HID 32
#define OUT_CH 16
#define NPW 128           // nodes per bucket (col >> 7)
#define NPW_SHIFT 7
#define NB_MAX 1024
#define CAPF 12800        // fill_sort LDS edge capacity (50 KB)
#define FBT 512           // threads in hist/fill
#define CAP 12288         // csr_sort LDS edge capacity (48 KB)
#define SCAN_CHUNK 1024
#define NXCD 8
#define EPT 8

typedef int vint4 __attribute__((ext_vector_type(4)));
typedef vint4 vint4u __attribute__((aligned(4)));

// ---------------------------------------------------------------------------
__global__ void detect_dtype(const void* ei, long long ecount, int n, int* flag) {
    int lane = threadIdx.x;
    const long long* p = (const long long*)ei;
    long long st = ecount / 64; if (st < 1) st = 1;
    long long idx = (long long)lane * st;
    bool ok = true;
    if (idx < ecount) {
        long long v = p[idx];
        ok = (v >= 0 && v < n);
    }
    unsigned long long mask = __ballot(ok);
    if (lane == 0) *flag = (mask == ~0ULL) ? 1 : 0;
}

__device__ __forceinline__ int load_idx(const void* ei, long long i, int is64) {
    return is64 ? (int)((const long long*)ei)[i] : ((const int*)ei)[i];
}

__device__ __forceinline__ void load_idx8_nt(const void* ei, long long off, int is64,
                                             int* c) {
    if (is64) {
        const long long* p = (const long long*)ei + off;
#pragma unroll
        for (int j = 0; j < 8; ++j) c[j] = (int)__builtin_nontemporal_load(p + j);
    } else {
        vint4 v0 = __builtin_nontemporal_load((const vint4*)((const int*)ei + off));
        vint4 v1 = __builtin_nontemporal_load((const vint4*)((const int*)ei + off + 4));
        c[0] = v0.x; c[1] = v0.y; c[2] = v0.z; c[3] = v0.w;
        c[4] = v1.x; c[5] = v1.y; c[6] = v1.z; c[7] = v1.w;
    }
}

__device__ __forceinline__ float bf_lo(unsigned int u) { return __uint_as_float(u << 16); }
__device__ __forceinline__ float bf_hi(unsigned int u) { return __uint_as_float(u & 0xFFFF0000u); }

// ---------------------------------------------------------------------------
__global__ __launch_bounds__(256) void zero_int(int* p, int n) {
    int i = blockIdx.x * 256 + threadIdx.x;
    if (i < n) p[i] = 0;
}

__global__ __launch_bounds__(256) void zero_float(float* p, long long n) {
    long long i = (long long)blockIdx.x * 256 + threadIdx.x;
    if (i < n) p[i] = 0.f;
}

// ---------------------------------------------------------------------------
// pass A: per-block LDS histogram -> bhist[bucket*fbgrid+blk]
// ---------------------------------------------------------------------------
__global__ __launch_bounds__(FBT) void bucket_hist(const void* ei, long long E,
                                                   const int* flag, int* bhist,
                                                   int nb, long long chunk, int fbgrid) {
    __shared__ int hist[NB_MAX];
    for (int i = threadIdx.x; i < nb; i += FBT) hist[i] = 0;
    __syncthreads();
    long long lo = (long long)blockIdx.x * chunk;
    long long hi = lo + chunk; if (hi > E) hi = E;
    int is64 = *flag;
    if ((E & 7) == 0) {
        for (long long e = lo + (long long)threadIdx.x * EPT; e + EPT <= hi;
             e += (long long)FBT * EPT) {
            int c[8]; load_idx8_nt(ei, E + e, is64, c);
#pragma unroll
            for (int j = 0; j < 8; ++j) atomicAdd(&hist[c[j] >> NPW_SHIFT], 1);
        }
    } else {
        for (long long e = lo + threadIdx.x; e < hi; e += FBT)
            atomicAdd(&hist[load_idx(ei, E + e, is64) >> NPW_SHIFT], 1);
    }
    __syncthreads();
    for (int b = threadIdx.x; b < nb; b += FBT)
        bhist[(long long)b * fbgrid + blockIdx.x] = hist[b];
}

// pass B: per-bucket exclusive scan over fbgrid block counts (coalesced) + totals
__global__ __launch_bounds__(256) void scan_blocks(int* bhist, int* btot, int nb,
                                                   int fbgrid) {
    __shared__ int sd[256];
    int b = blockIdx.x, t = threadIdx.x;
    int* p = bhist + (long long)b * fbgrid;
    int running = 0;
    for (int j0 = 0; j0 < fbgrid; j0 += 256) {
        int j = j0 + t;
        int v = (j < fbgrid) ? p[j] : 0;
        sd[t] = v; __syncthreads();
        for (int off = 1; off < 256; off <<= 1) {
            int u = (t >= off) ? sd[t - off] : 0;
            __syncthreads(); sd[t] += u; __syncthreads();
        }
        if (j < fbgrid) p[j] = running + sd[t] - v;
        int tot = sd[255];
        __syncthreads();
        running += tot;
    }
    if (t == 0) btot[b] = running;
}

// pass C: exclusive scan over nb bucket totals, one block
__global__ __launch_bounds__(1024) void scan_buckets(const int* btot, int* bstart, int nb) {
    __shared__ int sd[1024];
    int t = threadIdx.x;
    int a0 = (2 * t < nb) ? btot[2 * t] : 0;
    int a1 = (2 * t + 1 < nb) ? btot[2 * t + 1] : 0;
    sd[t] = a0 + a1; __syncthreads();
    for (int off = 1; off < 1024; off <<= 1) {
        int v = (t >= off) ? sd[t - off] : 0;
        __syncthreads(); sd[t] += v; __syncthreads();
    }
    int excl = sd[t] - (a0 + a1);
    if (2 * t < nb)     bstart[2 * t] = excl;
    if (2 * t + 1 < nb) bstart[2 * t + 1] = excl + a0;
    if (t == 1023) bstart[nb] = sd[t];
}

// ---------------------------------------------------------------------------
// pass D: sort-then-burst fill. Bucket-sort chunk in LDS, then burst-write
// each (bucket,block) run contiguously -> lines complete immediately, no
// long-lived partial-dirty lines (kills the 5x write amplification).
// ---------------------------------------------------------------------------
__global__ __launch_bounds__(FBT) void fill_sort(const void* ei, long long E,
                                                 const int* flag, const int* bhist,
                                                 const int* bstart, int* bucketed,
                                                 int nb, long long chunk, int fbgrid) {
    __shared__ int lds[CAPF];
    __shared__ int hist[NB_MAX];
    __shared__ int base[NB_MAX];
    __shared__ int cur[NB_MAX];
    int blk = blockIdx.x, t = threadIdx.x;
    long long lo = (long long)blk * chunk;
    long long hi = lo + chunk; if (hi > E) hi = E;
    int cnt = (int)(hi - lo);
    for (int i = t; i < nb; i += FBT) hist[i] = 0;
    __syncthreads();
    int is64 = *flag;
    bool vec = ((E & 7) == 0) && ((chunk & 7) == 0);

    // pass a: local hist of cols
    if (vec) {
        for (long long e = lo + (long long)t * EPT; e + EPT <= hi; e += (long long)FBT * EPT) {
            int c[8]; load_idx8_nt(ei, E + e, is64, c);
#pragma unroll
            for (int j = 0; j < 8; ++j) atomicAdd(&hist[c[j] >> NPW_SHIFT], 1);
        }
    } else {
        for (long long e = lo + t; e < hi; e += FBT)
            atomicAdd(&hist[load_idx(ei, E + e, is64) >> NPW_SHIFT], 1);
    }
    __syncthreads();

    if (cnt <= CAPF) {
        // local exclusive scan of hist (2 elems/thread, base[] doubles as scratch)
        int a0 = (2 * t < nb) ? hist[2 * t] : 0;
        int a1 = (2 * t + 1 < nb) ? hist[2 * t + 1] : 0;
        base[t] = a0 + a1; __syncthreads();
        for (int off = 1; off < FBT; off <<= 1) {
            int u = (t >= off) ? base[t - off] : 0;
            __syncthreads(); base[t] += u; __syncthreads();
        }
        int incl = base[t];
        __syncthreads();
        int excl = incl - (a0 + a1);
        if (2 * t < nb)     { base[2 * t] = excl;          cur[2 * t] = excl; }
        if (2 * t + 1 < nb) { base[2 * t + 1] = excl + a0; cur[2 * t + 1] = excl + a0; }
        __syncthreads();

        // pass b: scatter packed entries into bucket-sorted LDS
        if (vec) {
            for (long long e = lo + (long long)t * EPT; e + EPT <= hi; e += (long long)FBT * EPT) {
                int c[8], r[8];
                load_idx8_nt(ei, E + e, is64, c);
                load_idx8_nt(ei, e, is64, r);
#pragma unroll
                for (int j = 0; j < 8; ++j) {
                    int b = c[j] >> NPW_SHIFT;
                    int p = atomicAdd(&cur[b], 1);
                    lds[p] = r[j] | ((c[j] & (NPW - 1)) << 17);
                }
            }
        } else {
            for (long long e = lo + t; e < hi; e += FBT) {
                int col = load_idx(ei, E + e, is64);
                int row = load_idx(ei, e, is64);
                int b = col >> NPW_SHIFT;
                int p = atomicAdd(&cur[b], 1);
                lds[p] = row | ((col & (NPW - 1)) << 17);
            }
        }
        __syncthreads();

        // pass c: burst-write each bucket run (16-lane groups)
        int grp = t >> 4, lane = t & 15;       // 32 groups x 16 lanes
        for (int b = grp; b < nb; b += 32) {
            int l0 = base[b], c0 = hist[b];
            if (!c0) continue;
            int g0 = bstart[b] + bhist[(long long)b * fbgrid + blk];
            for (int j = lane; j < c0; j += 16)
                bucketed[g0 + j] = lds[l0 + j];
        }
    } else {
        // fallback: direct scatter (shouldn't trigger at expected sizes)
        for (int b = t; b < nb; b += FBT)
            cur[b] = bstart[b] + bhist[(long long)b * fbgrid + blk];
        __syncthreads();
        for (long long e = lo + t; e < hi; e += FBT) {
            int col = load_idx(ei, E + e, is64);
            int row = load_idx(ei, e, is64);
            int b = col >> NPW_SHIFT;
            int p = atomicAdd(&cur[b], 1);
            bucketed[p] = row | ((col & (NPW - 1)) << 17);
        }
    }
}

// ---------------------------------------------------------------------------
// per-bucket node sort: LDS-stage, NPW-node hist, emit offs/dinv + csr
// ---------------------------------------------------------------------------
__global__ __launch_bounds__(512) void csr_sort(const int* __restrict__ bucketed,
                                                const int* __restrict__ bstart,
                                                int* __restrict__ csr,
                                                int* __restrict__ offs,
                                                float* __restrict__ dinv,
                                                int nb, int n) {
    __shared__ int lds_e[CAP];
    __shared__ int hist[NPW];
    __shared__ int cur[NPW];
    int b = blockIdx.x, t = threadIdx.x;
    int s0 = bstart[b], s1 = bstart[b + 1];
    int cnt = s1 - s0;
    if (t < NPW) hist[t] = 0;
    __syncthreads();
    bool fit = (cnt <= CAP);
    int cnt4 = cnt & ~3;
    if (fit) {
        for (int i = t * 4; i < cnt4; i += 2048) {
            vint4u e4 = *(const vint4u*)(bucketed + s0 + i);
            lds_e[i + 0] = e4.x; atomicAdd(&hist[e4.x >> 17], 1);
            lds_e[i + 1] = e4.y; atomicAdd(&hist[e4.y >> 17], 1);
            lds_e[i + 2] = e4.z; atomicAdd(&hist[e4.z >> 17], 1);
            lds_e[i + 3] = e4.w; atomicAdd(&hist[e4.w >> 17], 1);
        }
        for (int i = cnt4 + t; i < cnt; i += 512) {
            int e = bucketed[s0 + i];
            lds_e[i] = e;
            atomicAdd(&hist[e >> 17], 1);
        }
    } else {
        for (int i = t * 4; i < cnt4; i += 2048) {
            vint4u e4 = *(const vint4u*)(bucketed + s0 + i);
            atomicAdd(&hist[e4.x >> 17], 1);
            atomicAdd(&hist[e4.y >> 17], 1);
            atomicAdd(&hist[e4.z >> 17], 1);
            atomicAdd(&hist[e4.w >> 17], 1);
        }
        for (int i = cnt4 + t; i < cnt; i += 512)
            atomicAdd(&hist[bucketed[s0 + i] >> 17], 1);
    }
    __syncthreads();
    if (t == 0) {
        int run = 0;
        for (int k = 0; k < NPW; ++k) { cur[k] = run; run += hist[k]; }
    }
    __syncthreads();
    if (t < NPW) {
        int node = b * NPW + t;
        if (node < n) {
            offs[node] = s0 + cur[t];
            dinv[node] = 1.0f / sqrtf((float)(hist[t] + 1));  // +1 self loop
        }
    }
    if (b == nb - 1 && t == 0) offs[n] = s1;
    __syncthreads();
    if (fit) {
        for (int i = t; i < cnt; i += 512) {
            int e = lds_e[i];
            int pos = atomicAdd(&cur[e >> 17], 1);
            csr[s0 + pos] = e & 0x1FFFF;
        }
    } else {
        for (int i = t; i < cnt; i += 512) {
            int e = bucketed[s0 + i];
            int pos = atomicAdd(&cur[e >> 17], 1);
            csr[s0 + pos] = e & 0x1FFFF;
        }
    }
}

// ---------------------------------------------------------------------------
// GEMMs, dinv pre-multiplied; BF16=1 writes bf16 (halves agg gather bytes)
// ---------------------------------------------------------------------------
template <int BF16>
__global__ __launch_bounds__(256) void gemm1p(const float* __restrict__ x,
                                              const float* __restrict__ W1,
                                              const float* __restrict__ dinv,
                                              float* __restrict__ m1f,
                                              __hip_bfloat16* __restrict__ m1b, int n) {
    __shared__ float sW[IN_CH * HID];
    __shared__ float sx[8][IN_CH];
    for (int i = threadIdx.x; i < IN_CH * HID; i += 256) sW[i] = W1[i];
    int g = threadIdx.x >> 5;
    int c = threadIdx.x & 31;
    long long node = (long long)blockIdx.x * 8 + g;
    bool active = node < n;
    if (active) {
        const float4* xr = (const float4*)(x + node * IN_CH);
        float4 v = xr[c];
        sx[g][c * 4 + 0] = v.x; sx[g][c * 4 + 1] = v.y;
        sx[g][c * 4 + 2] = v.z; sx[g][c * 4 + 3] = v.w;
    }
    __syncthreads();
    if (!active) return;
    float acc = 0.f;
#pragma unroll
    for (int k = 0; k < IN_CH; ++k)
        acc = fmaf(sx[g][k], sW[k * HID + c], acc);
    float v = acc * dinv[node];
    if (BF16) m1b[(node << 5) + c] = __float2bfloat16(v);
    else      m1f[(node << 5) + c] = v;
}

template <int BF16>
__global__ __launch_bounds__(256) void gemm2p(const float* __restrict__ h,
                                              const float* __restrict__ W2,
                                              const float* __restrict__ dinv,
                                              float* __restrict__ m2f,
                                              __hip_bfloat16* __restrict__ m2b, int n) {
    __shared__ float sW[HID * OUT_CH];
    for (int i = threadIdx.x; i < HID * OUT_CH; i += 256) sW[i] = W2[i];
    __syncthreads();
    long long t = (long long)blockIdx.x * 256 + threadIdx.x;
    long long node = t >> 4;
    int c = (int)(t & 15);
    if (node >= n) return;
    const float* hr = h + node * HID;
    float acc = 0.f;
#pragma unroll
    for (int k = 0; k < HID; ++k)
        acc = fmaf(hr[k], sW[k * OUT_CH + c], acc);
    float v = acc * dinv[node];
    if (BF16) m2b[(node << 4) + c] = __float2bfloat16(v);
    else      m2f[(node << 4) + c] = v;
}

// ---------------------------------------------------------------------------
// bf16 CSR gather aggregation
// ---------------------------------------------------------------------------
__global__ __launch_bounds__(256) void agg1_bf(const unsigned int* __restrict__ m1b,
                                               const int* __restrict__ csr,
                                               const int* __restrict__ offs,
                                               const float* __restrict__ dinv,
                                               const float* __restrict__ b1,
                                               float* __restrict__ h, int n) {
    int g = threadIdx.x >> 4;
    int c = threadIdx.x & 15;
    long long node = (long long)blockIdx.x * 16 + g;
    if (node >= n) return;
    unsigned int us = m1b[(node << 4) + c];          // self loop
    float accL = bf_lo(us), accH = bf_hi(us);
    int s = offs[node], e1 = offs[node + 1];
    for (; s + 7 < e1; s += 8) {
        vint4u a = *(const vint4u*)(csr + s);
        vint4u b = *(const vint4u*)(csr + s + 4);
        unsigned int u0 = m1b[((long long)a.x << 4) + c];
        unsigned int u1 = m1b[((long long)a.y << 4) + c];
        unsigned int u2 = m1b[((long long)a.z << 4) + c];
        unsigned int u3 = m1b[((long long)a.w << 4) + c];
        unsigned int u4 = m1b[((long long)b.x << 4) + c];
        unsigned int u5 = m1b[((long long)b.y << 4) + c];
        unsigned int u6 = m1b[((long long)b.z << 4) + c];
        unsigned int u7 = m1b[((long long)b.w << 4) + c];
        accL += bf_lo(u0); accH += bf_hi(u0);
        accL += bf_lo(u1); accH += bf_hi(u1);
        accL += bf_lo(u2); accH += bf_hi(u2);
        accL += bf_lo(u3); accH += bf_hi(u3);
        accL += bf_lo(u4); accH += bf_hi(u4);
        accL += bf_lo(u5); accH += bf_hi(u5);
        accL += bf_lo(u6); accH += bf_hi(u6);
        accL += bf_lo(u7); accH += bf_hi(u7);
    }
    for (; s < e1; ++s) {
        unsigned int u = m1b[((long long)csr[s] << 4) + c];
        accL += bf_lo(u); accH += bf_hi(u);
    }
    float di = dinv[node];
    float vL = accL * di + b1[2 * c];
    float vH = accH * di + b1[2 * c + 1];
    float2 val;
    val.x = vL > 0.f ? vL : 0.f;
    val.y = vH > 0.f ? vH : 0.f;
    *(float2*)(h + (node << 5) + 2 * c) = val;
}

__global__ __launch_bounds__(256) void agg2_bf(const unsigned int* __restrict__ m2b,
                                               const int* __restrict__ csr,
                                               const int* __restrict__ offs,
                                               const float* __restrict__ dinv,
                                               const float* __restrict__ b2,
                                               float* __restrict__ out, int n) {
    int g = threadIdx.x >> 3;
    int c = threadIdx.x & 7;
    long long node = (long long)blockIdx.x * 32 + g;
    if (node >= n) return;
    unsigned int us = m2b[(node << 3) + c];
    float accL = bf_lo(us), accH = bf_hi(us);
    int s = offs[node], e1 = offs[node + 1];
    for (; s + 7 < e1; s += 8) {
        vint4u a = *(const vint4u*)(csr + s);
        vint4u b = *(const vint4u*)(csr + s + 4);
        unsigned int u0 = m2b[((long long)a.x << 3) + c];
        unsigned int u1 = m2b[((long long)a.y << 3) + c];
        unsigned int u2 = m2b[((long long)a.z << 3) + c];
        unsigned int u3 = m2b[((long long)a.w << 3) + c];
        unsigned int u4 = m2b[((long long)b.x << 3) + c];
        unsigned int u5 = m2b[((long long)b.y << 3) + c];
        unsigned int u6 = m2b[((long long)b.z << 3) + c];
        unsigned int u7 = m2b[((long long)b.w << 3) + c];
        accL += bf_lo(u0); accH += bf_hi(u0);
        accL += bf_lo(u1); accH += bf_hi(u1);
        accL += bf_lo(u2); accH += bf_hi(u2);
        accL += bf_lo(u3); accH += bf_hi(u3);
        accL += bf_lo(u4); accH += bf_hi(u4);
        accL += bf_lo(u5); accH += bf_hi(u5);
        accL += bf_lo(u6); accH += bf_hi(u6);
        accL += bf_lo(u7); accH += bf_hi(u7);
    }
    for (; s < e1; ++s) {
        unsigned int u = m2b[((long long)csr[s] << 3) + c];
        accL += bf_lo(u); accH += bf_hi(u);
    }
    float di = dinv[node];
    float2 val;
    val.x = accL * di + b2[2 * c];
    val.y = accH * di + b2[2 * c + 1];
    *(float2*)(out + (node << 4) + 2 * c) = val;
}

// ---------------------------------------------------------------------------
// tier 2: windowed CSR fill path
// ---------------------------------------------------------------------------
__global__ __launch_bounds__(256) void count_edges(const void* ei, int* cnt,
                                                   long long E, const int* flag) {
    long long e0 = ((long long)blockIdx.x * 256 + threadIdx.x) * EPT;
    if (e0 >= E) return;
    int is64 = *flag;
    if (e0 + EPT <= E && (E & 7) == 0) {
        int c[EPT];
        load_idx8_nt(ei, E + e0, is64, c);
#pragma unroll
        for (int j = 0; j < EPT; ++j) atomicAdd(&cnt[c[j]], 1);
    } else {
        for (long long e = e0; e < E && e < e0 + EPT; ++e)
            atomicAdd(&cnt[load_idx(ei, E + e, is64)], 1);
    }
}

__global__ __launch_bounds__(256) void compute_dinv(const int* cnt, float* dinv, int n) {
    int i = blockIdx.x * 256 + threadIdx.x;
    if (i < n) dinv[i] = 1.0f / sqrtf((float)(cnt[i] + 1));
}

__global__ __launch_bounds__(256) void scan_partial(const int* cnt, int* partial, int n) {
    __shared__ int sd[256];
    int base = blockIdx.x * SCAN_CHUNK;
    int s = 0;
    for (int j = threadIdx.x; j < SCAN_CHUNK; j += 256) {
        int i = base + j;
        if (i < n) s += cnt[i];
    }
    sd[threadIdx.x] = s;
    __syncthreads();
    for (int off = 128; off > 0; off >>= 1) {
        if (threadIdx.x < off) sd[threadIdx.x] += sd[threadIdx.x + off];
        __syncthreads();
    }
    if (threadIdx.x == 0) partial[blockIdx.x] = sd[0];
}

__global__ void scan_serial(int* partial, int* offs, int nblk, int n) {
    if (threadIdx.x == 0 && blockIdx.x == 0) {
        int run = 0;
        for (int b = 0; b < nblk; ++b) { int t = partial[b]; partial[b] = run; run += t; }
        offs[n] = run;
    }
}

__global__ __launch_bounds__(256) void scan_final(const int* cnt, const int* partial,
                                                  int* offs, int n) {
    __shared__ int sd[256];
    int base = blockIdx.x * SCAN_CHUNK;
    int t = threadIdx.x;
    int loc[4]; int ts = 0;
#pragma unroll
    for (int j = 0; j < 4; ++j) {
        int i = base + t * 4 + j;
        loc[j] = (i < n) ? cnt[i] : 0;
        ts += loc[j];
    }
    sd[t] = ts;
    __syncthreads();
    for (int off = 1; off < 256; off <<= 1) {
        int v = (t >= off) ? sd[t - off] : 0;
        __syncthreads();
        sd[t] += v;
        __syncthreads();
    }
    int excl = sd[t] - ts + partial[blockIdx.x];
#pragma unroll
    for (int j = 0; j < 4; ++j) {
        int i = base + t * 4 + j;
        if (i < n) offs[i] = excl;
        excl += loc[j];
    }
}

__global__ __launch_bounds__(256) void copy_int(const int* src, int* dst, int n) {
    int i = blockIdx.x * 256 + threadIdx.x;
    if (i < n) dst[i] = src[i];
}

__global__ __launch_bounds__(256) void fill_csr_win(const void* ei, int* cursor, int* csr,
                                                    long long E, const int* flag,
                                                    int npw, int n) {
    int w = blockIdx.x & (NXCD - 1);
    int b = blockIdx.x >> 3;
    int lo = w * npw;
    int hi = lo + npw; if (hi > n) hi = n;
    long long e0 = ((long long)b * 256 + threadIdx.x) * EPT;
    if (e0 >= E) return;
    int is64 = *flag;
    if (e0 + EPT <= E && (E & 7) == 0) {
        int c[EPT];
        load_idx8_nt(ei, E + e0, is64, c);
#pragma unroll
        for (int j = 0; j < EPT; ++j) {
            if (c[j] >= lo && c[j] < hi) {
                int row = load_idx(ei, e0 + j, is64);
                int pos = atomicAdd(&cursor[c[j]], 1);
                csr[pos] = row;
            }
        }
    } else {
        for (long long e = e0; e < E && e < e0 + EPT; ++e) {
            int col = load_idx(ei, E + e, is64);
            if (col >= lo && col < hi) {
                int row = load_idx(ei, e, is64);
                int pos = atomicAdd(&cursor[col], 1);
                csr[pos] = row;
            }
        }
    }
}

// ---------------------------------------------------------------------------
// tier 3: scatter fallback (fp32, m pre-scaled)
// ---------------------------------------------------------------------------
__global__ __launch_bounds__(256) void scatter1(const float* __restrict__ m1s,
                                                const void* ei,
                                                float* __restrict__ h,
                                                long long E, const int* flag) {
    long long e = (long long)blockIdx.x * 8 + (threadIdx.x >> 5);
    int c = threadIdx.x & 31;
    if (e >= E) return;
    int is64 = *flag;
    int row = load_idx(ei, e, is64);
    int col = load_idx(ei, E + e, is64);
    atomicAdd(&h[(long long)col * HID + c], m1s[(long long)row * HID + c]);
}

__global__ __launch_bounds__(256) void fixup1(const float* __restrict__ m1s,
                                              const float* __restrict__ dinv,
                                              const float* __restrict__ b1,
                                              float* __restrict__ h, int n) {
    long long t = (long long)blockIdx.x * 256 + threadIdx.x;
    long long node = t >> 5; int c = (int)(t & 31);
    if (node >= n) return;
    float v = (h[node * HID + c] + m1s[node * HID + c]) * dinv[node] + b1[c];
    h[node * HID + c] = v > 0.f ? v : 0.f;
}

__global__ __launch_bounds__(256) void scatter2(const float* __restrict__ m2s,
                                                const void* ei,
                                                float* __restrict__ out,
                                                long long E, const int* flag) {
    long long e = (long long)blockIdx.x * 16 + (threadIdx.x >> 4);
    int c = threadIdx.x & 15;
    if (e >= E) return;
    int is64 = *flag;
    int row = load_idx(ei, e, is64);
    int col = load_idx(ei, E + e, is64);
    atomicAdd(&out[(long long)col * OUT_CH + c], m2s[(long long)row * OUT_CH + c]);
}

__global__ __launch_bounds__(256) void fixup2(const float* __restrict__ m2s,
                                              const float* __restrict__ dinv,
                                              const float* __restrict__ b2,
                                              float* __restrict__ out, int n) {
    long long t = (long long)blockIdx.x * 256 + threadIdx.x;
    long long node = t >> 4; int c = (int)(t & 15);
    if (node >= n) return;
    out[node * OUT_CH + c] = (out[node * OUT_CH + c] + m2s[node * OUT_CH + c]) * dinv[node] + b2[c];
}

// ---------------------------------------------------------------------------
extern "C" void kernel_launch(void* const* d_in, const int* in_sizes, int n_in,
                              void* d_out, int out_size, void* d_ws, size_t ws_size,
                              hipStream_t stream) {
    const float* x  = (const float*)d_in[0];
    const void*  ei = d_in[1];
    const float* W1 = (const float*)d_in[2];
    const float* b1 = (const float*)d_in[3];
    const float* W2 = (const float*)d_in[4];
    const float* b2 = (const float*)d_in[5];
    float* out = (float*)d_out;

    const int n = in_sizes[0] / IN_CH;           // 100000
    const long long E = in_sizes[1] / 2;         // 6400000
    const int nb = (n + NPW - 1) / NPW;          // 782

    // fill geometry: chunk fits CAPF, 8-aligned; fbgrid derived
    const long long chunkF = (((E + 511) / 512) + 7) & ~7LL;
    const int fbgrid = (int)((E + chunkF - 1) / chunkF);

    char* w = (char*)d_ws;
    size_t used = 0;
    auto carve = [&](size_t bytes) -> void* {
        void* p = (void*)(w + used);
        used += (bytes + 255) & ~(size_t)255;
        return p;
    };
    auto A = [](size_t b) -> size_t { return (b + 255) & ~(size_t)255; };

    int*   bstart  = (int*)carve((size_t)(NB_MAX + 1) * 4);
    int*   btot    = (int*)carve((size_t)NB_MAX * 4);
    float* dinv    = (float*)carve((size_t)n * 4);
    int*   flag    = (int*)carve(256);
    int*   offs    = (int*)carve((size_t)(n + 1) * 4);
    int*   cnt     = (int*)carve((size_t)n * 4);
    int*   partial = (int*)carve(4096);
    const size_t base = used;

    const size_t bhistB = A((size_t)nb * fbgrid * 4);
    const size_t mbB    = A((size_t)n * HID * 2);   // bf16 m1 (reused as m2)
    const size_t hB     = A((size_t)n * HID * 4);
    const size_t needT1 = base + bhistB + 2 * A((size_t)E * 4) + mbB + hB;
    const size_t needT2 = base + A((size_t)E * 4) + mbB + hB;
    const size_t needT3 = base + 2 * A((size_t)n * HID * 4);
    const bool tier1 = (ws_size >= needT1) && (n <= 131071) && (nb <= NB_MAX) &&
                       (chunkF <= CAPF || true);   // fallback path handles oversize
    const bool tier2 = !tier1 && (ws_size >= needT2) && (n <= 131071);

    const int nblkN  = (n + 255) / 256;
    const int nblkEv = (int)((E + 256LL * EPT - 1) / (256LL * EPT));
    const int nblkSc = (n + SCAN_CHUNK - 1) / SCAN_CHUNK;
    const int nblkH  = (int)(((long long)n * HID + 255) / 256);
    const int nblkO  = (int)(((long long)n * OUT_CH + 255) / 256);

    detect_dtype<<<1, 64, 0, stream>>>(ei, E, n, flag);

    if (tier1) {
        int*   bhist    = (int*)carve((size_t)nb * fbgrid * 4);
        int*   bucketed = (int*)carve((size_t)E * 4);
        int*   csr      = (int*)carve((size_t)E * 4);
        __hip_bfloat16* m1b = (__hip_bfloat16*)carve((size_t)n * HID * 2);
        float* h  = (float*)carve((size_t)n * HID * 4);
        __hip_bfloat16* m2b = m1b;                 // m1b dead after agg1

        bucket_hist<<<fbgrid, FBT, 0, stream>>>(ei, E, flag, bhist, nb, chunkF, fbgrid);
        scan_blocks<<<nb, 256, 0, stream>>>(bhist, btot, nb, fbgrid);
        scan_buckets<<<1, 1024, 0, stream>>>(btot, bstart, nb);
        fill_sort<<<fbgrid, FBT, 0, stream>>>(ei, E, flag, bhist, bstart,
                                              bucketed, nb, chunkF, fbgrid);
        csr_sort<<<nb, 512, 0, stream>>>(bucketed, bstart, csr, offs, dinv, nb, n);

        gemm1p<1><<<(n + 7) / 8, 256, 0, stream>>>(x, W1, dinv, nullptr, m1b, n);
        agg1_bf<<<(n + 15) / 16, 256, 0, stream>>>((const unsigned int*)m1b, csr, offs,
                                                   dinv, b1, h, n);
        gemm2p<1><<<nblkO, 256, 0, stream>>>(h, W2, dinv, nullptr, m2b, n);
        agg2_bf<<<(n + 31) / 32, 256, 0, stream>>>((const unsigned int*)m2b, csr, offs,
                                                   dinv, b2, out, n);
    } else if (tier2) {
        int*   csr = (int*)carve((size_t)E * 4);
        __hip_bfloat16* m1b = (__hip_bfloat16*)carve((size_t)n * HID * 2);
        float* h  = (float*)carve((size_t)n * HID * 4);
        __hip_bfloat16* m2b = m1b;

        zero_int<<<nblkN, 256, 0, stream>>>(cnt, n);
        count_edges<<<nblkEv, 256, 0, stream>>>(ei, cnt, E, flag);
        compute_dinv<<<nblkN, 256, 0, stream>>>(cnt, dinv, n);
        scan_partial<<<nblkSc, 256, 0, stream>>>(cnt, partial, n);
        scan_serial<<<1, 64, 0, stream>>>(partial, offs, nblkSc, n);
        scan_final<<<nblkSc, 256, 0, stream>>>(cnt, partial, offs, n);
        copy_int<<<nblkN, 256, 0, stream>>>(offs, cnt, n);

        const int npw2 = (n + NXCD - 1) / NXCD;
        fill_csr_win<<<nblkEv * NXCD, 256, 0, stream>>>(ei, cnt, csr, E, flag, npw2, n);

        gemm1p<1><<<(n + 7) / 8, 256, 0, stream>>>(x, W1, dinv, nullptr, m1b, n);
        agg1_bf<<<(n + 15) / 16, 256, 0, stream>>>((const unsigned int*)m1b, csr, offs,
                                                   dinv, b1, h, n);
        gemm2p<1><<<nblkO, 256, 0, stream>>>(h, W2, dinv, nullptr, m2b, n);
        agg2_bf<<<(n + 31) / 32, 256, 0, stream>>>((const unsigned int*)m2b, csr, offs,
                                                   dinv, b2, out, n);
    } else if (ws_size >= needT3) {
        float* m1 = (float*)carve((size_t)n * HID * 4);
        float* h  = (float*)carve((size_t)n * HID * 4);
        float* m2 = m1;

        zero_int<<<nblkN, 256, 0, stream>>>(cnt, n);
        count_edges<<<nblkEv, 256, 0, stream>>>(ei, cnt, E, flag);
        compute_dinv<<<nblkN, 256, 0, stream>>>(cnt, dinv, n);

        gemm1p<0><<<(n + 7) / 8, 256, 0, stream>>>(x, W1, dinv, m1, nullptr, n);
        zero_float<<<nblkH, 256, 0, stream>>>(h, (long long)n * HID);
        scatter1<<<(int)((E + 7) / 8), 256, 0, stream>>>(m1, ei, h, E, flag);
        fixup1<<<nblkH, 256, 0, stream>>>(m1, dinv, b1, h, n);
        gemm2p<0><<<nblkO, 256, 0, stream>>>(h, W2, dinv, m2, nullptr, n);
        zero_float<<<nblkO, 256, 0, stream>>>(out, (long long)n * OUT_CH);
        scatter2<<<(int)((E + 15) / 16), 256, 0, stream>>>(m2, ei, out, E, flag);
        fixup2<<<nblkO, 256, 0, stream>>>(m2, dinv, b2, out, n);
    }
}